// Round 14
// baseline (3722.906 us; speedup 1.0000x reference)
//
#include <hip/hip_runtime.h>
#include <hip/hip_bf16.h>
#include <math.h>

#define V 10000
#define E 512
#define H 1024
#define T 128
#define B 64
#define NWG 256
#define LDK 1032     // LDS row stride in ushorts (2064 B)
#define RHSLOTS 32   // rh rotation depth (fresh-address protocol, eviction-safe)

typedef __bf16 bf16x8 __attribute__((ext_vector_type(8)));
typedef float f32x4 __attribute__((ext_vector_type(4)));
typedef unsigned short ushort8 __attribute__((ext_vector_type(8)));

// ---------------------------------------------------------------------------
// Cache-bypassing (coherent-at-MALL) access helpers (validated R4-R13).
// ---------------------------------------------------------------------------
__device__ __forceinline__ void store_f32_sc(float* p, float v) {
    asm volatile("global_store_dword %0, %1, off sc0 sc1" :: "v"(p), "v"(v) : "memory");
}
__device__ __forceinline__ void store_u16_sc(unsigned short* p, unsigned v) {
    asm volatile("global_store_short %0, %1, off sc0 sc1" :: "v"(p), "v"(v) : "memory");
}
__device__ __forceinline__ int load_i32_sc(const int* p) {
    int r;
    asm volatile("global_load_dword %0, %1, off sc0 sc1\n\ts_waitcnt vmcnt(0)"
                 : "=v"(r) : "v"(p) : "memory");
    return r;
}

// ---------------------------------------------------------------------------
// Per-m-tile-group grid barrier: 64 blocks/group, 8 stripes (validated R12-13).
// ---------------------------------------------------------------------------
__device__ __forceinline__ void gridbar_grp(int* gcnt, int gen) {
    asm volatile("s_waitcnt vmcnt(0)" ::: "memory");
    __syncthreads();
    if (threadIdx.x == 0)
        __hip_atomic_fetch_add(gcnt + (blockIdx.x & 7) * 32, 1,
                               __ATOMIC_RELAXED, __HIP_MEMORY_SCOPE_AGENT);
    if (threadIdx.x < 8) {
        const int target = gen * 8;
        while (load_i32_sc(gcnt + threadIdx.x * 32) < target)
            __builtin_amdgcn_s_sleep(2);
    }
    __syncthreads();
}

// ---------------------------------------------------------------------------
// Split: fp32 -> truncated-hi bf16 + residual-lo bf16 (deterministic).
// ---------------------------------------------------------------------------
__device__ inline void splitpack(float4 v, uint2& hi, uint2& lo) {
    unsigned u0 = __float_as_uint(v.x), u1 = __float_as_uint(v.y);
    unsigned u2 = __float_as_uint(v.z), u3 = __float_as_uint(v.w);
    hi.x = __builtin_amdgcn_perm(u1, u0, 0x07060302u);
    hi.y = __builtin_amdgcn_perm(u3, u2, 0x07060302u);
    float l0 = v.x - __uint_as_float(u0 & 0xFFFF0000u);
    float l1 = v.y - __uint_as_float(u1 & 0xFFFF0000u);
    float l2 = v.z - __uint_as_float(u2 & 0xFFFF0000u);
    float l3 = v.w - __uint_as_float(u3 & 0xFFFF0000u);
    lo.x = __builtin_amdgcn_perm(__float_as_uint(l1), __float_as_uint(l0), 0x07060302u);
    lo.y = __builtin_amdgcn_perm(__float_as_uint(l3), __float_as_uint(l2), 0x07060302u);
}
__device__ inline void split1(float f, unsigned& hi, unsigned& lo) {
    unsigned u = __float_as_uint(f);
    hi = u >> 16;
    float l = f - __uint_as_float(u & 0xFFFF0000u);
    lo = __float_as_uint(l) >> 16;
}

__device__ __forceinline__ bf16x8 ld8(const unsigned short* p) {
    return __builtin_bit_cast(bf16x8, *(const ushort8*)p);
}
__device__ __forceinline__ f32x4 mfma3(f32x4 acc, bf16x8 ah, bf16x8 al,
                                       bf16x8 bh, bf16x8 bl) {
    acc = __builtin_amdgcn_mfma_f32_16x16x32_bf16(ah, bh, acc, 0, 0, 0);
    acc = __builtin_amdgcn_mfma_f32_16x16x32_bf16(al, bh, acc, 0, 0, 0);
    acc = __builtin_amdgcn_mfma_f32_16x16x32_bf16(ah, bl, acc, 0, 0, 0);
    return acc;
}

// ---------------------------------------------------------------------------
// Fused prepass: split all weights + hidden into bf16 hi/lo (one launch).
// ---------------------------------------------------------------------------
struct SplitSeg { const float* src; unsigned short* hi; unsigned short* lo; unsigned end; };
struct SplitTab { SplitSeg s[14]; };

__global__ __launch_bounds__(256) void split_all(SplitTab tab) {
    unsigned idx = blockIdx.x * 256 + threadIdx.x;
    unsigned base = 0;
    #pragma unroll
    for (int i = 0; i < 14; ++i) {
        if (idx < tab.s[i].end) {
            unsigned off = idx - base;
            float4 v = ((const float4*)tab.s[i].src)[off];
            uint2 h, l;
            splitpack(v, h, l);
            ((uint2*)tab.s[i].hi)[off] = h;
            ((uint2*)tab.s[i].lo)[off] = l;
            return;
        }
        base = tab.s[i].end;
    }
}

// ---------------------------------------------------------------------------
// Batched 3-gate Wx GEMM, pre-split B; A either fp32 (gather+split: emb) or
// pre-split (h0). gridDim.z = 3 selects gate. N = H exact. C [M][3H] fp32.
// ---------------------------------------------------------------------------
__global__ __launch_bounds__(256) void gemm_wx3h(
    const float* __restrict__ Af32,
    const unsigned short* __restrict__ Ahi, const unsigned short* __restrict__ Alo,
    const unsigned short* __restrict__ Whi, const unsigned short* __restrict__ Wlo,
    const float* __restrict__ b0, const float* __restrict__ b1, const float* __restrict__ b2,
    float* __restrict__ C, const int* __restrict__ rowidx, int K)
{
    __shared__ __align__(16) unsigned short Ah[128 * 40];
    __shared__ __align__(16) unsigned short Al[128 * 40];
    __shared__ __align__(16) unsigned short Bh[128 * 40];
    __shared__ __align__(16) unsigned short Bl[128 * 40];

    const int z = blockIdx.z;
    const float* __restrict__ bias = (z == 0) ? b0 : (z == 1) ? b1 : b2;
    const size_t zo = (size_t)z * H * K;

    const int tid  = threadIdx.x;
    const int lane = tid & 63;
    const int wv   = tid >> 6;
    const int wm   = wv & 1, wn = wv >> 1;
    const int bn = blockIdx.x * 128;
    const int bm = blockIdx.y * 128;

    const float* apt[4];
    unsigned lofs4[4];
    if (Af32) {
        #pragma unroll
        for (int i = 0; i < 4; ++i) {
            int f4 = i * 256 + tid, r = f4 >> 3, kq = f4 & 7;
            int gm = bm + r;
            int ar = rowidx ? rowidx[gm] : gm;
            apt[i] = Af32 + (size_t)ar * K + kq * 4;
            lofs4[i] = r * 40 + kq * 4;
        }
    }

    f32x4 acc[4][4];
    #pragma unroll
    for (int i = 0; i < 4; ++i)
        #pragma unroll
        for (int j = 0; j < 4; ++j) acc[i][j] = (f32x4){0.f, 0.f, 0.f, 0.f};

    const int la  = lane & 15;
    const int kg8 = (lane >> 4) * 8;

    for (int k0 = 0; k0 < K; k0 += 32) {
        __syncthreads();
        if (Af32) {
            #pragma unroll
            for (int i = 0; i < 4; ++i) {
                float4 va = *(const float4*)(apt[i] + k0);
                uint2 h, l;
                splitpack(va, h, l);
                *(uint2*)&Ah[lofs4[i]] = h;
                *(uint2*)&Al[lofs4[i]] = l;
            }
        } else {
            #pragma unroll
            for (int i = 0; i < 2; ++i) {
                int u8 = i * 256 + tid, r = u8 >> 2, c = (u8 & 3) * 8;
                *(ushort8*)&Ah[r * 40 + c] = *(const ushort8*)(Ahi + (size_t)(bm + r) * K + k0 + c);
                *(ushort8*)&Al[r * 40 + c] = *(const ushort8*)(Alo + (size_t)(bm + r) * K + k0 + c);
            }
        }
        #pragma unroll
        for (int i = 0; i < 2; ++i) {
            int u8 = i * 256 + tid, r = u8 >> 2, c = (u8 & 3) * 8;
            *(ushort8*)&Bh[r * 40 + c] = *(const ushort8*)(Whi + zo + (size_t)(bn + r) * K + k0 + c);
            *(ushort8*)&Bl[r * 40 + c] = *(const ushort8*)(Wlo + zo + (size_t)(bn + r) * K + k0 + c);
        }
        __syncthreads();

        bf16x8 ah[4], al[4];
        #pragma unroll
        for (int mt = 0; mt < 4; ++mt) {
            int row = (wm * 64 + mt * 16 + la) * 40 + kg8;
            ah[mt] = ld8(&Ah[row]);
            al[mt] = ld8(&Al[row]);
        }
        #pragma unroll
        for (int nt = 0; nt < 4; ++nt) {
            int row = (wn * 64 + nt * 16 + la) * 40 + kg8;
            bf16x8 bh = ld8(&Bh[row]);
            bf16x8 bl = ld8(&Bl[row]);
            #pragma unroll
            for (int mt = 0; mt < 4; ++mt)
                acc[mt][nt] = mfma3(acc[mt][nt], ah[mt], al[mt], bh, bl);
        }
    }

    #pragma unroll
    for (int mt = 0; mt < 4; ++mt) {
        int mrow = bm + wm * 64 + mt * 16 + (lane >> 4) * 4;
        #pragma unroll
        for (int nt = 0; nt < 4; ++nt) {
            int n = bn + wn * 64 + nt * 16 + la;
            float bi = bias[n];
            #pragma unroll
            for (int r = 0; r < 4; ++r)
                C[(size_t)(mrow + r) * (3 * H) + n + z * H] = acc[mt][nt][r] + bi;
        }
    }
}

// ---------------------------------------------------------------------------
// Logits GEMM: fully pre-split A (h1) and B (Wout). N bounds-checked.
// ---------------------------------------------------------------------------
__global__ __launch_bounds__(256) void gemm_logits(
    const unsigned short* __restrict__ Ahi, const unsigned short* __restrict__ Alo,
    const unsigned short* __restrict__ Bhi, const unsigned short* __restrict__ Blo,
    const float* __restrict__ bias, float* __restrict__ C, int N, int K)
{
    __shared__ __align__(16) unsigned short Ah[128 * 40];
    __shared__ __align__(16) unsigned short Al[128 * 40];
    __shared__ __align__(16) unsigned short Bh[128 * 40];
    __shared__ __align__(16) unsigned short Bl[128 * 40];

    const int tid  = threadIdx.x;
    const int lane = tid & 63;
    const int wv   = tid >> 6;
    const int wm   = wv & 1, wn = wv >> 1;
    const int bn = blockIdx.x * 128;
    const int bm = blockIdx.y * 128;

    f32x4 acc[4][4];
    #pragma unroll
    for (int i = 0; i < 4; ++i)
        #pragma unroll
        for (int j = 0; j < 4; ++j) acc[i][j] = (f32x4){0.f, 0.f, 0.f, 0.f};

    const int la  = lane & 15;
    const int kg8 = (lane >> 4) * 8;

    for (int k0 = 0; k0 < K; k0 += 32) {
        __syncthreads();
        #pragma unroll
        for (int i = 0; i < 2; ++i) {
            int u8 = i * 256 + tid, r = u8 >> 2, c = (u8 & 3) * 8;
            *(ushort8*)&Ah[r * 40 + c] = *(const ushort8*)(Ahi + (size_t)(bm + r) * K + k0 + c);
            *(ushort8*)&Al[r * 40 + c] = *(const ushort8*)(Alo + (size_t)(bm + r) * K + k0 + c);
            int brow = bn + r;
            int br = (brow < N) ? brow : 0;
            *(ushort8*)&Bh[r * 40 + c] = *(const ushort8*)(Bhi + (size_t)br * K + k0 + c);
            *(ushort8*)&Bl[r * 40 + c] = *(const ushort8*)(Blo + (size_t)br * K + k0 + c);
        }
        __syncthreads();

        bf16x8 ah[4], al[4];
        #pragma unroll
        for (int mt = 0; mt < 4; ++mt) {
            int row = (wm * 64 + mt * 16 + la) * 40 + kg8;
            ah[mt] = ld8(&Ah[row]);
            al[mt] = ld8(&Al[row]);
        }
        #pragma unroll
        for (int nt = 0; nt < 4; ++nt) {
            int row = (wn * 64 + nt * 16 + la) * 40 + kg8;
            bf16x8 bh = ld8(&Bh[row]);
            bf16x8 bl = ld8(&Bl[row]);
            #pragma unroll
            for (int mt = 0; mt < 4; ++mt)
                acc[mt][nt] = mfma3(acc[mt][nt], ah[mt], al[mt], bh, bl);
        }
    }

    #pragma unroll
    for (int mt = 0; mt < 4; ++mt) {
        int mrow = bm + wm * 64 + mt * 16 + (lane >> 4) * 4;
        #pragma unroll
        for (int nt = 0; nt < 4; ++nt) {
            int n = bn + wn * 64 + nt * 16 + la;
            if (n < N) {
                float bi = bias[n];
                #pragma unroll
                for (int r = 0; r < 4; ++r)
                    C[(size_t)(mrow + r) * N + n] = acc[mt][nt][r] + bi;
            }
        }
    }
}

// ---------------------------------------------------------------------------
// Persistent single-layer GRU. XCD-resident U; 4 independent 64-block m-tile
// groups; 256 blocks x 1024 threads (4 waves/SIMD). Pre-split exchange:
// producers store h / r*h as bf16 hi+lo (sc0sc1); consumers plain-copy into
// padded LDS (zero staging VALU). Register-carried h + 1-step Wx prefetch.
// ---------------------------------------------------------------------------
__global__ __launch_bounds__(1024, 1) void gru_layer(
    const unsigned short* __restrict__ Uhi, const unsigned short* __restrict__ Ulo,
    const float* __restrict__ Wx, const float* __restrict__ hinit,
    const unsigned short* __restrict__ hstg_hi, const unsigned short* __restrict__ hstg_lo,
    unsigned short* __restrict__ h_hi, unsigned short* __restrict__ h_lo,
    unsigned short* __restrict__ rh_hi, unsigned short* __restrict__ rh_lo,
    float* __restrict__ hfin, int* cnt)
{
    extern __shared__ char smem[];
    unsigned short* hs_hi = (unsigned short*)smem;       // 16*LDK
    unsigned short* hs_lo = hs_hi + 16 * LDK;
    f32x4* red = (f32x4*)(hs_lo + 16 * LDK);             // 30*64 f32x4

    const int tid  = threadIdx.x;
    const int lane = tid & 63;
    const int kh   = __builtin_amdgcn_readfirstlane(tid >> 6);  // k-16th 0..15
    const int la   = lane & 15;
    const int kg8  = (lane >> 4) * 8;
    const int erow = (lane >> 4) * 4;

    const int bid = blockIdx.x;
    const int xcd = bid & 7;
    const int sub = bid >> 3;
    const int grp = sub & 3;
    const int m0  = grp * 16;
    const int j0  = (xcd * 8 + (sub >> 2)) * 16;
    int* gcnt = cnt + grp * 8 * 32;

    const size_t HH = (size_t)H * H;
    const unsigned short* Ur_hi = Uhi;
    const unsigned short* Uz_hi = Uhi + HH;
    const unsigned short* Uh_hi = Uhi + 2 * HH;
    const unsigned short* Ur_lo = Ulo;
    const unsigned short* Uz_lo = Ulo + HH;
    const unsigned short* Uh_lo = Ulo + 2 * HH;

    int gen = 0;
    const int rbase = m0 + erow;

    f32x4 zreg = (f32x4){0.f, 0.f, 0.f, 0.f};
    float hvC[4] = {0.f, 0.f, 0.f, 0.f};
    float wrC[4], wzC[4], whC[4];
    float wrN[4], wzN[4], whN[4];
    if (kh == 0) {
        #pragma unroll
        for (int qq = 0; qq < 4; ++qq) {
            hvC[qq] = hinit[(size_t)(rbase + qq) * H + j0 + la];
            const size_t wb = ((size_t)0 * B + rbase + qq) * (3 * H) + j0 + la;
            wrC[qq] = Wx[wb];
            wzC[qq] = Wx[wb + H];
            whC[qq] = Wx[wb + 2 * H];
        }
    }

    for (int t = 0; t < T; ++t) {
        const size_t rbs = (size_t)(t & (RHSLOTS - 1)) * B * H;

        // ================= phase A: r, z =================
        {
            const unsigned short* ph = (t == 0) ? hstg_hi : (h_hi + (size_t)(t - 1) * B * H);
            const unsigned short* pl = (t == 0) ? hstg_lo : (h_lo + (size_t)(t - 1) * B * H);
            #pragma unroll
            for (int j = 0; j < 2; ++j) {
                int u8 = j * 1024 + tid;
                int r = u8 >> 7, c = (u8 & 127) * 8;
                *(ushort8*)&hs_hi[r * LDK + c] = *(const ushort8*)(ph + (size_t)(m0 + r) * H + c);
                *(ushort8*)&hs_lo[r * LDK + c] = *(const ushort8*)(pl + (size_t)(m0 + r) * H + c);
            }
            __syncthreads();
            f32x4 a0 = (f32x4){0.f, 0.f, 0.f, 0.f}, a1 = a0;
            const int kb = kh * 64 + kg8;
            #pragma unroll
            for (int ks = 0; ks < 2; ++ks) {
                const int ko = kb + ks * 32;
                const int ar = la * LDK + ko;
                bf16x8 ah = ld8(&hs_hi[ar]);
                bf16x8 al = ld8(&hs_lo[ar]);
                const size_t ub = (size_t)(j0 + la) * H + ko;
                a0 = mfma3(a0, ah, al, ld8(Ur_hi + ub), ld8(Ur_lo + ub));
                a1 = mfma3(a1, ah, al, ld8(Uz_hi + ub), ld8(Uz_lo + ub));
            }
            if (kh) {
                red[((kh - 1) * 2 + 0) * 64 + lane] = a0;
                red[((kh - 1) * 2 + 1) * 64 + lane] = a1;
            }
            __syncthreads();
            if (kh == 0) {
                #pragma unroll
                for (int w = 0; w < 15; ++w) {
                    a0 += red[(w * 2 + 0) * 64 + lane];
                    a1 += red[(w * 2 + 1) * 64 + lane];
                }
                #pragma unroll
                for (int qq = 0; qq < 4; ++qq) {
                    float rg = 1.f / (1.f + __expf(-(a0[qq] + wrC[qq])));
                    zreg[qq] = 1.f / (1.f + __expf(-(a1[qq] + wzC[qq])));
                    float rh = rg * hvC[qq];
                    unsigned rhh, rhl;
                    split1(rh, rhh, rhl);
                    const size_t ix = rbs + (size_t)(rbase + qq) * H + j0 + la;
                    store_u16_sc(rh_hi + ix, rhh);
                    store_u16_sc(rh_lo + ix, rhl);
                }
            }
        }
        gridbar_grp(gcnt, ++gen);

        // ================= phase B: h~ and update =================
        {
            if (kh == 0 && t + 1 < T) {
                #pragma unroll
                for (int qq = 0; qq < 4; ++qq) {
                    const size_t wb = ((size_t)(t + 1) * B + rbase + qq) * (3 * H) + j0 + la;
                    wrN[qq] = Wx[wb];
                    wzN[qq] = Wx[wb + H];
                    whN[qq] = Wx[wb + 2 * H];
                }
            }
            #pragma unroll
            for (int j = 0; j < 2; ++j) {
                int u8 = j * 1024 + tid;
                int r = u8 >> 7, c = (u8 & 127) * 8;
                *(ushort8*)&hs_hi[r * LDK + c] = *(const ushort8*)(rh_hi + rbs + (size_t)(m0 + r) * H + c);
                *(ushort8*)&hs_lo[r * LDK + c] = *(const ushort8*)(rh_lo + rbs + (size_t)(m0 + r) * H + c);
            }
            __syncthreads();
            f32x4 a = (f32x4){0.f, 0.f, 0.f, 0.f};
            const int kb = kh * 64 + kg8;
            #pragma unroll
            for (int ks = 0; ks < 2; ++ks) {
                const int ko = kb + ks * 32;
                const int ar = la * LDK + ko;
                const size_t ub = (size_t)(j0 + la) * H + ko;
                a = mfma3(a, ld8(&hs_hi[ar]), ld8(&hs_lo[ar]),
                          ld8(Uh_hi + ub), ld8(Uh_lo + ub));
            }
            if (kh) red[(kh - 1) * 64 + lane] = a;
            __syncthreads();
            if (kh == 0) {
                #pragma unroll
                for (int w = 0; w < 15; ++w) a += red[w * 64 + lane];
                #pragma unroll
                for (int qq = 0; qq < 4; ++qq) {
                    float ht = tanhf(a[qq] + whC[qq]);
                    float hn = (1.f - zreg[qq]) * hvC[qq] + zreg[qq] * ht;
                    unsigned hh, hl;
                    split1(hn, hh, hl);
                    const size_t ix = (size_t)t * B * H + (size_t)(rbase + qq) * H + j0 + la;
                    store_u16_sc(h_hi + ix, hh);
                    store_u16_sc(h_lo + ix, hl);
                    if (t == T - 1)
                        store_f32_sc(hfin + (size_t)(rbase + qq) * H + j0 + la, hn);
                    hvC[qq] = hn;
                    wrC[qq] = wrN[qq];
                    wzC[qq] = wzN[qq];
                    whC[qq] = whN[qq];
                }
            }
        }
        gridbar_grp(gcnt, ++gen);
    }
}

// ---------------------------------------------------------------------------
extern "C" void kernel_launch(void* const* d_in, const int* in_sizes, int n_in,
                              void* d_out, int out_size, void* d_ws, size_t ws_size,
                              hipStream_t stream)
{
    const int*   tok    = (const int*)d_in[0];
    const float* hidden = (const float*)d_in[1];
    const float* emb    = (const float*)d_in[2];
    const float* Wr0 = (const float*)d_in[3],  *br0 = (const float*)d_in[4];
    const float* Wz0 = (const float*)d_in[5],  *bz0 = (const float*)d_in[6];
    const float* Wh0 = (const float*)d_in[7],  *bh0 = (const float*)d_in[8];
    const float* Ur0 = (const float*)d_in[9],  *Uz0 = (const float*)d_in[10], *Uh0 = (const float*)d_in[11];
    const float* Wr1 = (const float*)d_in[12], *br1 = (const float*)d_in[13];
    const float* Wz1 = (const float*)d_in[14], *bz1 = (const float*)d_in[15];
    const float* Wh1 = (const float*)d_in[16], *bh1 = (const float*)d_in[17];
    const float* Ur1 = (const float*)d_in[18], *Uz1 = (const float*)d_in[19], *Uh1 = (const float*)d_in[20];
    const float* Wout = (const float*)d_in[21], *bout = (const float*)d_in[22];
    float* out = (float*)d_out;

    const size_t HH = (size_t)H * H;
    const size_t HE = (size_t)H * E;
    const size_t TBH = (size_t)T * B * H;
    const size_t VH = (size_t)V * H;

    float* ws = (float*)d_ws;
    float* Wx = ws;                                      // T*B*3H fp32
    unsigned short* u16 = (unsigned short*)(Wx + 3 * TBH);
    unsigned short* U0hi = u16;            u16 += 3 * HH;
    unsigned short* U0lo = u16;            u16 += 3 * HH;
    unsigned short* U1hi = u16;            u16 += 3 * HH;
    unsigned short* U1lo = u16;            u16 += 3 * HH;
    unsigned short* W1hi = u16;            u16 += 3 * HH;
    unsigned short* W1lo = u16;            u16 += 3 * HH;
    unsigned short* W0hi = u16;            u16 += 3 * HE;
    unsigned short* W0lo = u16;            u16 += 3 * HE;
    unsigned short* Wouthi = u16;          u16 += VH;
    unsigned short* Woutlo = u16;          u16 += VH;
    unsigned short* hidhi = u16;           u16 += 2 * (size_t)B * H;
    unsigned short* hidlo = u16;           u16 += 2 * (size_t)B * H;
    unsigned short* h0hi = u16;            u16 += TBH;
    unsigned short* h0lo = u16;            u16 += TBH;
    unsigned short* h1hi = u16;            u16 += TBH;
    unsigned short* h1lo = u16;            u16 += TBH;
    unsigned short* rh0hi = u16;           u16 += (size_t)RHSLOTS * B * H;
    unsigned short* rh0lo = u16;           u16 += (size_t)RHSLOTS * B * H;
    unsigned short* rh1hi = u16;           u16 += (size_t)RHSLOTS * B * H;
    unsigned short* rh1lo = u16;           u16 += (size_t)RHSLOTS * B * H;
    int* cnt0 = (int*)u16;
    int* cnt1 = cnt0 + 4 * 8 * 32;

    static bool attr_set = false;
    if (!attr_set) {
        (void)hipFuncSetAttribute((const void*)gru_layer,
                                  hipFuncAttributeMaxDynamicSharedMemorySize, 96768);
        attr_set = true;
    }

    (void)hipMemsetAsync(cnt0, 0, 2 * 4 * 8 * 32 * sizeof(int), stream);

    // ---- fused prepass split (14 segments, one launch) ----
    const unsigned nU = (unsigned)(HH / 4), nW0 = (unsigned)(HE / 4);
    const unsigned nWout = (unsigned)(VH / 4), nHid = (unsigned)(2 * B * H / 4);
    SplitTab tab;
    unsigned acc = 0;
    const float* srcs[14] = {Ur0, Uz0, Uh0, Ur1, Uz1, Uh1, Wr1, Wz1, Wh1,
                             Wr0, Wz0, Wh0, Wout, hidden};
    unsigned short* his[14] = {U0hi, U0hi + HH, U0hi + 2 * HH, U1hi, U1hi + HH, U1hi + 2 * HH,
                               W1hi, W1hi + HH, W1hi + 2 * HH,
                               W0hi, W0hi + HE, W0hi + 2 * HE, Wouthi, hidhi};
    unsigned short* los[14] = {U0lo, U0lo + HH, U0lo + 2 * HH, U1lo, U1lo + HH, U1lo + 2 * HH,
                               W1lo, W1lo + HH, W1lo + 2 * HH,
                               W0lo, W0lo + HE, W0lo + 2 * HE, Woutlo, hidlo};
    unsigned cnts[14] = {nU, nU, nU, nU, nU, nU, nU, nU, nU, nW0, nW0, nW0, nWout, nHid};
    for (int i = 0; i < 14; ++i) {
        acc += cnts[i];
        tab.s[i] = {srcs[i], his[i], los[i], acc};
    }
    split_all<<<acc / 256, 256, 0, stream>>>(tab);

    // ---- Wx(L0) = emb[tok] @ W0^T + b (A fp32 gather path) ----
    gemm_wx3h<<<dim3(H / 128, T * B / 128, 3), 256, 0, stream>>>(
        emb, nullptr, nullptr, W0hi, W0lo, br0, bz0, bh0, Wx, tok, E);

    gru_layer<<<NWG, 1024, 96768, stream>>>(
        U0hi, U0lo, Wx, hidden, hidhi, hidlo,
        h0hi, h0lo, rh0hi, rh0lo, out + (size_t)T * B * V, cnt0);

    // ---- Wx(L1) = h0 @ W1^T + b (pre-split A) ----
    gemm_wx3h<<<dim3(H / 128, T * B / 128, 3), 256, 0, stream>>>(
        nullptr, h0hi, h0lo, W1hi, W1lo, br1, bz1, bh1, Wx, nullptr, H);

    gru_layer<<<NWG, 1024, 96768, stream>>>(
        U1hi, U1lo, Wx, hidden + (size_t)B * H, hidhi + (size_t)B * H, hidlo + (size_t)B * H,
        h1hi, h1lo, rh1hi, rh1lo, out + (size_t)T * B * V + (size_t)B * H, cnt1);

    // ---- logits = h1 @ Wout^T + bout (fully pre-split) ----
    gemm_logits<<<dim3((V + 127) / 128, T * B / 128), 256, 0, stream>>>(
        h1hi, h1lo, Wouthi, Woutlo, bout, out, V, H);
}

// Round 15
// 3497.820 us; speedup vs baseline: 1.0644x; 1.0644x over previous
//
#include <hip/hip_runtime.h>
#include <hip/hip_bf16.h>
#include <math.h>

#define V 10000
#define E 512
#define H 1024
#define T 128
#define B 64
#define NWG 256
#define LDK 1032   // LDS row stride in ushorts (2064 B)

typedef __bf16 bf16x8 __attribute__((ext_vector_type(8)));
typedef float f32x4 __attribute__((ext_vector_type(4)));
typedef unsigned short ushort8 __attribute__((ext_vector_type(8)));

// ---------------------------------------------------------------------------
// Cache-bypassing (coherent-at-MALL) access helpers (validated R4-R13).
// ---------------------------------------------------------------------------
__device__ __forceinline__ void store_f32_sc(float* p, float v) {
    asm volatile("global_store_dword %0, %1, off sc0 sc1" :: "v"(p), "v"(v) : "memory");
}
__device__ __forceinline__ int load_i32_sc(const int* p) {
    int r;
    asm volatile("global_load_dword %0, %1, off sc0 sc1\n\ts_waitcnt vmcnt(0)"
                 : "=v"(r) : "v"(p) : "memory");
    return r;
}

// ---------------------------------------------------------------------------
// Per-m-tile-group grid barrier: 64 blocks/group, 8 stripes (validated R12-13).
// ---------------------------------------------------------------------------
__device__ __forceinline__ void gridbar_grp(int* gcnt, int gen) {
    asm volatile("s_waitcnt vmcnt(0)" ::: "memory");
    __syncthreads();
    if (threadIdx.x == 0)
        __hip_atomic_fetch_add(gcnt + (blockIdx.x & 7) * 32, 1,
                               __ATOMIC_RELAXED, __HIP_MEMORY_SCOPE_AGENT);
    if (threadIdx.x < 8) {
        const int target = gen * 8;
        while (load_i32_sc(gcnt + threadIdx.x * 32) < target)
            __builtin_amdgcn_s_sleep(2);
    }
    __syncthreads();
}

// ---------------------------------------------------------------------------
// Split: fp32 -> truncated-hi bf16 + residual-lo bf16 (deterministic).
// ---------------------------------------------------------------------------
__device__ inline void splitpack(float4 v, uint2& hi, uint2& lo) {
    unsigned u0 = __float_as_uint(v.x), u1 = __float_as_uint(v.y);
    unsigned u2 = __float_as_uint(v.z), u3 = __float_as_uint(v.w);
    hi.x = __builtin_amdgcn_perm(u1, u0, 0x07060302u);
    hi.y = __builtin_amdgcn_perm(u3, u2, 0x07060302u);
    float l0 = v.x - __uint_as_float(u0 & 0xFFFF0000u);
    float l1 = v.y - __uint_as_float(u1 & 0xFFFF0000u);
    float l2 = v.z - __uint_as_float(u2 & 0xFFFF0000u);
    float l3 = v.w - __uint_as_float(u3 & 0xFFFF0000u);
    lo.x = __builtin_amdgcn_perm(__float_as_uint(l1), __float_as_uint(l0), 0x07060302u);
    lo.y = __builtin_amdgcn_perm(__float_as_uint(l3), __float_as_uint(l2), 0x07060302u);
}

__device__ __forceinline__ bf16x8 ld8(const unsigned short* p) {
    return __builtin_bit_cast(bf16x8, *(const ushort8*)p);
}
__device__ __forceinline__ f32x4 mfma3(f32x4 acc, bf16x8 ah, bf16x8 al,
                                       bf16x8 bh, bf16x8 bl) {
    acc = __builtin_amdgcn_mfma_f32_16x16x32_bf16(ah, bh, acc, 0, 0, 0);
    acc = __builtin_amdgcn_mfma_f32_16x16x32_bf16(al, bh, acc, 0, 0, 0);
    acc = __builtin_amdgcn_mfma_f32_16x16x32_bf16(ah, bl, acc, 0, 0, 0);
    return acc;
}

// ---------------------------------------------------------------------------
// Fused prepass: split all weights into bf16 hi/lo (one launch, 13 segments).
// ---------------------------------------------------------------------------
struct SplitSeg { const float* src; unsigned short* hi; unsigned short* lo; unsigned end; };
struct SplitTab { SplitSeg s[13]; };

__global__ __launch_bounds__(256) void split_all(SplitTab tab) {
    unsigned idx = blockIdx.x * 256 + threadIdx.x;
    unsigned base = 0;
    #pragma unroll
    for (int i = 0; i < 13; ++i) {
        if (idx < tab.s[i].end) {
            unsigned off = idx - base;
            float4 v = ((const float4*)tab.s[i].src)[off];
            uint2 h, l;
            splitpack(v, h, l);
            ((uint2*)tab.s[i].hi)[off] = h;
            ((uint2*)tab.s[i].lo)[off] = l;
            return;
        }
        base = tab.s[i].end;
    }
}

// ---------------------------------------------------------------------------
// Batched 3-gate Wx GEMM: A fp32 (optional row gather), B pre-split bf16.
// gridDim.z = 3 selects gate; N = H exact; C [M][3H] fp32 + bias.
// ---------------------------------------------------------------------------
__global__ __launch_bounds__(256) void gemm_wx3h(
    const float* __restrict__ A,
    const unsigned short* __restrict__ Whi, const unsigned short* __restrict__ Wlo,
    const float* __restrict__ b0, const float* __restrict__ b1, const float* __restrict__ b2,
    float* __restrict__ C, const int* __restrict__ rowidx, int K)
{
    __shared__ __align__(16) unsigned short Ah[128 * 40];
    __shared__ __align__(16) unsigned short Al[128 * 40];
    __shared__ __align__(16) unsigned short Bh[128 * 40];
    __shared__ __align__(16) unsigned short Bl[128 * 40];

    const int z = blockIdx.z;
    const float* __restrict__ bias = (z == 0) ? b0 : (z == 1) ? b1 : b2;
    const size_t zo = (size_t)z * H * K;

    const int tid  = threadIdx.x;
    const int lane = tid & 63;
    const int wv   = tid >> 6;
    const int wm   = wv & 1, wn = wv >> 1;
    const int bn = blockIdx.x * 128;
    const int bm = blockIdx.y * 128;

    const float* apt[4];
    unsigned lofs4[4];
    #pragma unroll
    for (int i = 0; i < 4; ++i) {
        int f4 = i * 256 + tid, r = f4 >> 3, kq = f4 & 7;
        int gm = bm + r;
        int ar = rowidx ? rowidx[gm] : gm;
        apt[i] = A + (size_t)ar * K + kq * 4;
        lofs4[i] = r * 40 + kq * 4;
    }

    f32x4 acc[4][4];
    #pragma unroll
    for (int i = 0; i < 4; ++i)
        #pragma unroll
        for (int j = 0; j < 4; ++j) acc[i][j] = (f32x4){0.f, 0.f, 0.f, 0.f};

    const int la  = lane & 15;
    const int kg8 = (lane >> 4) * 8;

    for (int k0 = 0; k0 < K; k0 += 32) {
        __syncthreads();
        #pragma unroll
        for (int i = 0; i < 4; ++i) {
            float4 va = *(const float4*)(apt[i] + k0);
            uint2 h, l;
            splitpack(va, h, l);
            *(uint2*)&Ah[lofs4[i]] = h;
            *(uint2*)&Al[lofs4[i]] = l;
        }
        #pragma unroll
        for (int i = 0; i < 2; ++i) {
            int u8 = i * 256 + tid, r = u8 >> 2, c = (u8 & 3) * 8;
            *(ushort8*)&Bh[r * 40 + c] = *(const ushort8*)(Whi + zo + (size_t)(bn + r) * K + k0 + c);
            *(ushort8*)&Bl[r * 40 + c] = *(const ushort8*)(Wlo + zo + (size_t)(bn + r) * K + k0 + c);
        }
        __syncthreads();

        bf16x8 ah[4], al[4];
        #pragma unroll
        for (int mt = 0; mt < 4; ++mt) {
            int row = (wm * 64 + mt * 16 + la) * 40 + kg8;
            ah[mt] = ld8(&Ah[row]);
            al[mt] = ld8(&Al[row]);
        }
        #pragma unroll
        for (int nt = 0; nt < 4; ++nt) {
            int row = (wn * 64 + nt * 16 + la) * 40 + kg8;
            bf16x8 bh = ld8(&Bh[row]);
            bf16x8 bl = ld8(&Bl[row]);
            #pragma unroll
            for (int mt = 0; mt < 4; ++mt)
                acc[mt][nt] = mfma3(acc[mt][nt], ah[mt], al[mt], bh, bl);
        }
    }

    #pragma unroll
    for (int mt = 0; mt < 4; ++mt) {
        int mrow = bm + wm * 64 + mt * 16 + (lane >> 4) * 4;
        #pragma unroll
        for (int nt = 0; nt < 4; ++nt) {
            int n = bn + wn * 64 + nt * 16 + la;
            float bi = bias[n];
            #pragma unroll
            for (int r = 0; r < 4; ++r)
                C[(size_t)(mrow + r) * (3 * H) + n + z * H] = acc[mt][nt][r] + bi;
        }
    }
}

// ---------------------------------------------------------------------------
// Logits GEMM: A fp32 (h1), B pre-split (Wout). N bounds-checked.
// ---------------------------------------------------------------------------
__global__ __launch_bounds__(256) void gemm_logits(
    const float* __restrict__ A,
    const unsigned short* __restrict__ Bhi, const unsigned short* __restrict__ Blo,
    const float* __restrict__ bias, float* __restrict__ C, int N, int K)
{
    __shared__ __align__(16) unsigned short Ah[128 * 40];
    __shared__ __align__(16) unsigned short Al[128 * 40];
    __shared__ __align__(16) unsigned short Bh[128 * 40];
    __shared__ __align__(16) unsigned short Bl[128 * 40];

    const int tid  = threadIdx.x;
    const int lane = tid & 63;
    const int wv   = tid >> 6;
    const int wm   = wv & 1, wn = wv >> 1;
    const int bn = blockIdx.x * 128;
    const int bm = blockIdx.y * 128;

    const float* apt[4];
    unsigned lofs4[4];
    #pragma unroll
    for (int i = 0; i < 4; ++i) {
        int f4 = i * 256 + tid, r = f4 >> 3, kq = f4 & 7;
        apt[i] = A + (size_t)(bm + r) * K + kq * 4;
        lofs4[i] = r * 40 + kq * 4;
    }

    f32x4 acc[4][4];
    #pragma unroll
    for (int i = 0; i < 4; ++i)
        #pragma unroll
        for (int j = 0; j < 4; ++j) acc[i][j] = (f32x4){0.f, 0.f, 0.f, 0.f};

    const int la  = lane & 15;
    const int kg8 = (lane >> 4) * 8;

    for (int k0 = 0; k0 < K; k0 += 32) {
        __syncthreads();
        #pragma unroll
        for (int i = 0; i < 4; ++i) {
            float4 va = *(const float4*)(apt[i] + k0);
            uint2 h, l;
            splitpack(va, h, l);
            *(uint2*)&Ah[lofs4[i]] = h;
            *(uint2*)&Al[lofs4[i]] = l;
        }
        #pragma unroll
        for (int i = 0; i < 2; ++i) {
            int u8 = i * 256 + tid, r = u8 >> 2, c = (u8 & 3) * 8;
            int brow = bn + r;
            int br = (brow < N) ? brow : 0;
            *(ushort8*)&Bh[r * 40 + c] = *(const ushort8*)(Bhi + (size_t)br * K + k0 + c);
            *(ushort8*)&Bl[r * 40 + c] = *(const ushort8*)(Blo + (size_t)br * K + k0 + c);
        }
        __syncthreads();

        bf16x8 ah[4], al[4];
        #pragma unroll
        for (int mt = 0; mt < 4; ++mt) {
            int row = (wm * 64 + mt * 16 + la) * 40 + kg8;
            ah[mt] = ld8(&Ah[row]);
            al[mt] = ld8(&Al[row]);
        }
        #pragma unroll
        for (int nt = 0; nt < 4; ++nt) {
            int row = (wn * 64 + nt * 16 + la) * 40 + kg8;
            bf16x8 bh = ld8(&Bh[row]);
            bf16x8 bl = ld8(&Bl[row]);
            #pragma unroll
            for (int mt = 0; mt < 4; ++mt)
                acc[mt][nt] = mfma3(acc[mt][nt], ah[mt], al[mt], bh, bl);
        }
    }

    #pragma unroll
    for (int mt = 0; mt < 4; ++mt) {
        int mrow = bm + wm * 64 + mt * 16 + (lane >> 4) * 4;
        #pragma unroll
        for (int nt = 0; nt < 4; ++nt) {
            int n = bn + wn * 64 + nt * 16 + la;
            if (n < N) {
                float bi = bias[n];
                #pragma unroll
                for (int r = 0; r < 4; ++r)
                    C[(size_t)(mrow + r) * N + n] = acc[mt][nt][r] + bi;
            }
        }
    }
}

// ---------------------------------------------------------------------------
// Persistent single-layer GRU — exact R13 structure (measured 1295 us).
// XCD-resident U; 4 independent 64-block m-tile groups; 256 blocks x 1024
// threads (4 waves/SIMD). fp32 exchange via sc0sc1 + fresh-address reads;
// consumer-side splitpack; register-carried h + 1-step Wx prefetch.
// ---------------------------------------------------------------------------
__global__ __launch_bounds__(1024, 1) void gru_layer(
    const unsigned short* __restrict__ Uhi, const unsigned short* __restrict__ Ulo,
    const float* __restrict__ Wx, const float* __restrict__ hinit,
    float* __restrict__ hRM, float* __restrict__ rhRM,
    float* __restrict__ hfin, int* cnt)
{
    extern __shared__ char smem[];
    unsigned short* hs_hi = (unsigned short*)smem;       // 16*LDK
    unsigned short* hs_lo = hs_hi + 16 * LDK;
    f32x4* red = (f32x4*)(hs_lo + 16 * LDK);             // 30*64 f32x4

    const int tid  = threadIdx.x;
    const int lane = tid & 63;
    const int kh   = __builtin_amdgcn_readfirstlane(tid >> 6);  // k-16th 0..15
    const int la   = lane & 15;
    const int kg8  = (lane >> 4) * 8;
    const int erow = (lane >> 4) * 4;
    const int trow = tid >> 6;      // staging row 0..15
    const int tq   = tid & 63;      // staging f4 col group

    const int bid = blockIdx.x;
    const int xcd = bid & 7;
    const int sub = bid >> 3;
    const int grp = sub & 3;
    const int m0  = grp * 16;
    const int j0  = (xcd * 8 + (sub >> 2)) * 16;
    int* gcnt = cnt + grp * 8 * 32;

    const size_t HH = (size_t)H * H;
    const unsigned short* Ur_hi = Uhi;
    const unsigned short* Uz_hi = Uhi + HH;
    const unsigned short* Uh_hi = Uhi + 2 * HH;
    const unsigned short* Ur_lo = Ulo;
    const unsigned short* Uz_lo = Ulo + HH;
    const unsigned short* Uh_lo = Ulo + 2 * HH;

    int gen = 0;
    const int rbase = m0 + erow;

    f32x4 zreg = (f32x4){0.f, 0.f, 0.f, 0.f};
    float hvC[4] = {0.f, 0.f, 0.f, 0.f};
    float wrC[4], wzC[4], whC[4];
    float wrN[4], wzN[4], whN[4];
    if (kh == 0) {
        #pragma unroll
        for (int qq = 0; qq < 4; ++qq) {
            hvC[qq] = hinit[(size_t)(rbase + qq) * H + j0 + la];
            const size_t wb = ((size_t)0 * B + rbase + qq) * (3 * H) + j0 + la;
            wrC[qq] = Wx[wb];
            wzC[qq] = Wx[wb + H];
            whC[qq] = Wx[wb + 2 * H];
        }
    }

    for (int t = 0; t < T; ++t) {
        const float* hprev = (t == 0) ? hinit : (hRM + (size_t)(t - 1) * B * H);

        // ================= phase A: r, z =================
        {
            {
                const float* hrp = hprev + (size_t)(m0 + trow) * H;
                #pragma unroll
                for (int i = 0; i < 4; ++i) {
                    const int c = (tq + i * 64) * 4;
                    float4 v = *(const float4*)(hrp + c);
                    uint2 h2, l2;
                    splitpack(v, h2, l2);
                    *(uint2*)&hs_hi[trow * LDK + c] = h2;
                    *(uint2*)&hs_lo[trow * LDK + c] = l2;
                }
            }
            __syncthreads();
            f32x4 a0 = (f32x4){0.f, 0.f, 0.f, 0.f}, a1 = a0;
            const int kb = kh * 64 + kg8;
            #pragma unroll
            for (int ks = 0; ks < 2; ++ks) {
                const int ko = kb + ks * 32;
                const int ar = la * LDK + ko;
                bf16x8 ah = ld8(&hs_hi[ar]);
                bf16x8 al = ld8(&hs_lo[ar]);
                const size_t ub = (size_t)(j0 + la) * H + ko;
                a0 = mfma3(a0, ah, al, ld8(Ur_hi + ub), ld8(Ur_lo + ub));
                a1 = mfma3(a1, ah, al, ld8(Uz_hi + ub), ld8(Uz_lo + ub));
            }
            if (kh) {
                red[((kh - 1) * 2 + 0) * 64 + lane] = a0;
                red[((kh - 1) * 2 + 1) * 64 + lane] = a1;
            }
            __syncthreads();
            if (kh == 0) {
                #pragma unroll
                for (int w = 0; w < 15; ++w) {
                    a0 += red[(w * 2 + 0) * 64 + lane];
                    a1 += red[(w * 2 + 1) * 64 + lane];
                }
                #pragma unroll
                for (int qq = 0; qq < 4; ++qq) {
                    float rg = 1.f / (1.f + __expf(-(a0[qq] + wrC[qq])));
                    zreg[qq] = 1.f / (1.f + __expf(-(a1[qq] + wzC[qq])));
                    store_f32_sc(rhRM + ((size_t)t * B + rbase + qq) * H + j0 + la,
                                 rg * hvC[qq]);
                }
            }
        }
        gridbar_grp(gcnt, ++gen);

        // ================= phase B: h~ and update =================
        {
            if (kh == 0 && t + 1 < T) {
                #pragma unroll
                for (int qq = 0; qq < 4; ++qq) {
                    const size_t wb = ((size_t)(t + 1) * B + rbase + qq) * (3 * H) + j0 + la;
                    wrN[qq] = Wx[wb];
                    wzN[qq] = Wx[wb + H];
                    whN[qq] = Wx[wb + 2 * H];
                }
            }
            {
                const float* rrp = rhRM + (size_t)t * B * H + (size_t)(m0 + trow) * H;
                #pragma unroll
                for (int i = 0; i < 4; ++i) {
                    const int c = (tq + i * 64) * 4;
                    float4 v = *(const float4*)(rrp + c);
                    uint2 h2, l2;
                    splitpack(v, h2, l2);
                    *(uint2*)&hs_hi[trow * LDK + c] = h2;
                    *(uint2*)&hs_lo[trow * LDK + c] = l2;
                }
            }
            __syncthreads();
            f32x4 a = (f32x4){0.f, 0.f, 0.f, 0.f};
            const int kb = kh * 64 + kg8;
            #pragma unroll
            for (int ks = 0; ks < 2; ++ks) {
                const int ko = kb + ks * 32;
                const int ar = la * LDK + ko;
                const size_t ub = (size_t)(j0 + la) * H + ko;
                a = mfma3(a, ld8(&hs_hi[ar]), ld8(&hs_lo[ar]),
                          ld8(Uh_hi + ub), ld8(Uh_lo + ub));
            }
            if (kh) red[(kh - 1) * 64 + lane] = a;
            __syncthreads();
            if (kh == 0) {
                #pragma unroll
                for (int w = 0; w < 15; ++w) a += red[w * 64 + lane];
                #pragma unroll
                for (int qq = 0; qq < 4; ++qq) {
                    float ht = tanhf(a[qq] + whC[qq]);
                    float hn = (1.f - zreg[qq]) * hvC[qq] + zreg[qq] * ht;
                    store_f32_sc(hRM + ((size_t)t * B + rbase + qq) * H + j0 + la, hn);
                    if (t == T - 1)
                        store_f32_sc(hfin + (size_t)(rbase + qq) * H + j0 + la, hn);
                    hvC[qq] = hn;
                    wrC[qq] = wrN[qq];
                    wzC[qq] = wzN[qq];
                    whC[qq] = whN[qq];
                }
            }
        }
        gridbar_grp(gcnt, ++gen);
    }
}

// ---------------------------------------------------------------------------
extern "C" void kernel_launch(void* const* d_in, const int* in_sizes, int n_in,
                              void* d_out, int out_size, void* d_ws, size_t ws_size,
                              hipStream_t stream)
{
    const int*   tok    = (const int*)d_in[0];
    const float* hidden = (const float*)d_in[1];
    const float* emb    = (const float*)d_in[2];
    const float* Wr0 = (const float*)d_in[3],  *br0 = (const float*)d_in[4];
    const float* Wz0 = (const float*)d_in[5],  *bz0 = (const float*)d_in[6];
    const float* Wh0 = (const float*)d_in[7],  *bh0 = (const float*)d_in[8];
    const float* Ur0 = (const float*)d_in[9],  *Uz0 = (const float*)d_in[10], *Uh0 = (const float*)d_in[11];
    const float* Wr1 = (const float*)d_in[12], *br1 = (const float*)d_in[13];
    const float* Wz1 = (const float*)d_in[14], *bz1 = (const float*)d_in[15];
    const float* Wh1 = (const float*)d_in[16], *bh1 = (const float*)d_in[17];
    const float* Ur1 = (const float*)d_in[18], *Uz1 = (const float*)d_in[19], *Uh1 = (const float*)d_in[20];
    const float* Wout = (const float*)d_in[21], *bout = (const float*)d_in[22];
    float* out = (float*)d_out;

    const size_t HH = (size_t)H * H;
    const size_t HE = (size_t)H * E;
    const size_t TBH = (size_t)T * B * H;
    const size_t VH = (size_t)V * H;

    float* ws = (float*)d_ws;
    float* Wx    = ws;                                   // T*B*3H
    float* h0RM  = Wx    + 3 * TBH;
    float* rh0RM = h0RM  + TBH;
    float* h1RM  = rh0RM + TBH;
    float* rh1RM = h1RM  + TBH;
    unsigned short* u16 = (unsigned short*)(rh1RM + TBH);
    unsigned short* U0hi = u16;    u16 += 3 * HH;
    unsigned short* U0lo = u16;    u16 += 3 * HH;
    unsigned short* U1hi = u16;    u16 += 3 * HH;
    unsigned short* U1lo = u16;    u16 += 3 * HH;
    unsigned short* W1hi = u16;    u16 += 3 * HH;
    unsigned short* W1lo = u16;    u16 += 3 * HH;
    unsigned short* W0hi = u16;    u16 += 3 * HE;
    unsigned short* W0lo = u16;    u16 += 3 * HE;
    unsigned short* Wouthi = u16;  u16 += VH;
    unsigned short* Woutlo = u16;  u16 += VH;
    int* cnt0 = (int*)u16;
    int* cnt1 = cnt0 + 4 * 8 * 32;

    static bool attr_set = false;
    if (!attr_set) {
        (void)hipFuncSetAttribute((const void*)gru_layer,
                                  hipFuncAttributeMaxDynamicSharedMemorySize, 96768);
        attr_set = true;
    }

    (void)hipMemsetAsync(cnt0, 0, 2 * 4 * 8 * 32 * sizeof(int), stream);

    // ---- fused prepass split (13 segments, one launch) ----
    const unsigned nU = (unsigned)(HH / 4), nW0 = (unsigned)(HE / 4);
    const unsigned nWout = (unsigned)(VH / 4);
    SplitTab tab;
    unsigned acc = 0;
    const float* srcs[13] = {Ur0, Uz0, Uh0, Ur1, Uz1, Uh1, Wr1, Wz1, Wh1,
                             Wr0, Wz0, Wh0, Wout};
    unsigned short* his[13] = {U0hi, U0hi + HH, U0hi + 2 * HH, U1hi, U1hi + HH, U1hi + 2 * HH,
                               W1hi, W1hi + HH, W1hi + 2 * HH,
                               W0hi, W0hi + HE, W0hi + 2 * HE, Wouthi};
    unsigned short* los[13] = {U0lo, U0lo + HH, U0lo + 2 * HH, U1lo, U1lo + HH, U1lo + 2 * HH,
                               W1lo, W1lo + HH, W1lo + 2 * HH,
                               W0lo, W0lo + HE, W0lo + 2 * HE, Woutlo};
    unsigned cnts[13] = {nU, nU, nU, nU, nU, nU, nU, nU, nU, nW0, nW0, nW0, nWout};
    for (int i = 0; i < 13; ++i) {
        acc += cnts[i];
        tab.s[i] = {srcs[i], his[i], los[i], acc};
    }
    split_all<<<acc / 256, 256, 0, stream>>>(tab);

    // ---- Wx(L0) = emb[tok] @ W0^T + b (gather fused) ----
    gemm_wx3h<<<dim3(H / 128, T * B / 128, 3), 256, 0, stream>>>(
        emb, W0hi, W0lo, br0, bz0, bh0, Wx, tok, E);

    gru_layer<<<NWG, 1024, 96768, stream>>>(U0hi, U0lo, Wx, hidden,
                                            h0RM, rh0RM, out + (size_t)T * B * V, cnt0);

    // ---- Wx(L1) = h0 @ W1^T + b ----
    gemm_wx3h<<<dim3(H / 128, T * B / 128, 3), 256, 0, stream>>>(
        h0RM, W1hi, W1lo, br1, bz1, bh1, Wx, nullptr, H);

    gru_layer<<<NWG, 1024, 96768, stream>>>(U1hi, U1lo, Wx, hidden + (size_t)B * H,
                                            h1RM, rh1RM,
                                            out + (size_t)T * B * V + (size_t)B * H, cnt1);

    // ---- logits = h1 @ Wout^T + bout ----
    gemm_logits<<<dim3((V + 127) / 128, T * B / 128), 256, 0, stream>>>(
        h1RM, Wouthi, Woutlo, bout, out, V, H);
}

// Round 17
// 3312.597 us; speedup vs baseline: 1.1239x; 1.0559x over previous
//
#include <hip/hip_runtime.h>
#include <hip/hip_bf16.h>
#include <math.h>

#define V 10000
#define E 512
#define H 1024
#define T 128
#define B 64
#define NWG 256
#define LDK 1032   // LDS row stride in ushorts (2064 B)

typedef __bf16 bf16x8 __attribute__((ext_vector_type(8)));
typedef float f32x4 __attribute__((ext_vector_type(4)));
typedef unsigned short ushort8 __attribute__((ext_vector_type(8)));

// ---------------------------------------------------------------------------
// Cache-bypassing (coherent-at-MALL) access helpers (validated R4-R15).
// ---------------------------------------------------------------------------
__device__ __forceinline__ void store_f32_sc(float* p, float v) {
    asm volatile("global_store_dword %0, %1, off sc0 sc1" :: "v"(p), "v"(v) : "memory");
}
__device__ __forceinline__ int load_i32_sc(const int* p) {
    int r;
    asm volatile("global_load_dword %0, %1, off sc0 sc1\n\ts_waitcnt vmcnt(0)"
                 : "=v"(r) : "v"(p) : "memory");
    return r;
}

// ---------------------------------------------------------------------------
// Per-m-tile-group grid barrier: 64 blocks/group, 8 stripes (validated R12-15).
// ---------------------------------------------------------------------------
__device__ __forceinline__ void gridbar_grp(int* gcnt, int gen) {
    asm volatile("s_waitcnt vmcnt(0)" ::: "memory");
    __syncthreads();
    if (threadIdx.x == 0)
        __hip_atomic_fetch_add(gcnt + (blockIdx.x & 7) * 32, 1,
                               __ATOMIC_RELAXED, __HIP_MEMORY_SCOPE_AGENT);
    if (threadIdx.x < 8) {
        const int target = gen * 8;
        while (load_i32_sc(gcnt + threadIdx.x * 32) < target)
            __builtin_amdgcn_s_sleep(1);
    }
    __syncthreads();
}

// ---------------------------------------------------------------------------
// Split: fp32 -> truncated-hi bf16 + residual-lo bf16 (deterministic).
// lo selector MUST be 0x07060302 (top 16 bits of residual float) — R16 bug.
// ---------------------------------------------------------------------------
__device__ inline void splitpack(float4 v, uint2& hi, uint2& lo) {
    unsigned u0 = __float_as_uint(v.x), u1 = __float_as_uint(v.y);
    unsigned u2 = __float_as_uint(v.z), u3 = __float_as_uint(v.w);
    hi.x = __builtin_amdgcn_perm(u1, u0, 0x07060302u);
    hi.y = __builtin_amdgcn_perm(u3, u2, 0x07060302u);
    float l0 = v.x - __uint_as_float(u0 & 0xFFFF0000u);
    float l1 = v.y - __uint_as_float(u1 & 0xFFFF0000u);
    float l2 = v.z - __uint_as_float(u2 & 0xFFFF0000u);
    float l3 = v.w - __uint_as_float(u3 & 0xFFFF0000u);
    lo.x = __builtin_amdgcn_perm(__float_as_uint(l1), __float_as_uint(l0), 0x07060302u);
    lo.y = __builtin_amdgcn_perm(__float_as_uint(l3), __float_as_uint(l2), 0x07060302u);
}
// packed u32 = (hi16 << 16) | bf16(residual)
__device__ __forceinline__ unsigned pack1(float f) {
    unsigned u = __float_as_uint(f);
    float l = f - __uint_as_float(u & 0xFFFF0000u);
    return (u & 0xFFFF0000u) | (__float_as_uint(l) >> 16);
}
// unpack 4 packed values -> 4 hi ushorts (uint2) + 4 lo ushorts (uint2)
__device__ __forceinline__ void unpack4(uint4 p, uint2& hi, uint2& lo) {
    hi.x = __builtin_amdgcn_perm(p.y, p.x, 0x07060302u);
    hi.y = __builtin_amdgcn_perm(p.w, p.z, 0x07060302u);
    lo.x = __builtin_amdgcn_perm(p.y, p.x, 0x05040100u);
    lo.y = __builtin_amdgcn_perm(p.w, p.z, 0x05040100u);
}

__device__ __forceinline__ bf16x8 ld8(const unsigned short* p) {
    return __builtin_bit_cast(bf16x8, *(const ushort8*)p);
}
__device__ __forceinline__ f32x4 mfma3(f32x4 acc, bf16x8 ah, bf16x8 al,
                                       bf16x8 bh, bf16x8 bl) {
    acc = __builtin_amdgcn_mfma_f32_16x16x32_bf16(ah, bh, acc, 0, 0, 0);
    acc = __builtin_amdgcn_mfma_f32_16x16x32_bf16(al, bh, acc, 0, 0, 0);
    acc = __builtin_amdgcn_mfma_f32_16x16x32_bf16(ah, bl, acc, 0, 0, 0);
    return acc;
}

// ---------------------------------------------------------------------------
// Fused prepass: split all weights into bf16 hi/lo (one launch, 13 segments).
// ---------------------------------------------------------------------------
struct SplitSeg { const float* src; unsigned short* hi; unsigned short* lo; unsigned end; };
struct SplitTab { SplitSeg s[13]; };

__global__ __launch_bounds__(256) void split_all(SplitTab tab) {
    unsigned idx = blockIdx.x * 256 + threadIdx.x;
    unsigned base = 0;
    #pragma unroll
    for (int i = 0; i < 13; ++i) {
        if (idx < tab.s[i].end) {
            unsigned off = idx - base;
            float4 v = ((const float4*)tab.s[i].src)[off];
            uint2 h, l;
            splitpack(v, h, l);
            ((uint2*)tab.s[i].hi)[off] = h;
            ((uint2*)tab.s[i].lo)[off] = l;
            return;
        }
        base = tab.s[i].end;
    }
}

// ---------------------------------------------------------------------------
// Batched 3-gate Wx GEMM: B pre-split bf16. A either fp32 with gather (emb)
// or packed-split u32 (h0). gridDim.z = 3 selects gate; N = H exact.
// ---------------------------------------------------------------------------
__global__ __launch_bounds__(256) void gemm_wx3h(
    const float* __restrict__ Af32, const unsigned* __restrict__ Apk,
    const unsigned short* __restrict__ Whi, const unsigned short* __restrict__ Wlo,
    const float* __restrict__ b0, const float* __restrict__ b1, const float* __restrict__ b2,
    float* __restrict__ C, const int* __restrict__ rowidx, int K)
{
    __shared__ __align__(16) unsigned short Ah[128 * 40];
    __shared__ __align__(16) unsigned short Al[128 * 40];
    __shared__ __align__(16) unsigned short Bh[128 * 40];
    __shared__ __align__(16) unsigned short Bl[128 * 40];

    const int z = blockIdx.z;
    const float* __restrict__ bias = (z == 0) ? b0 : (z == 1) ? b1 : b2;
    const size_t zo = (size_t)z * H * K;

    const int tid  = threadIdx.x;
    const int lane = tid & 63;
    const int wv   = tid >> 6;
    const int wm   = wv & 1, wn = wv >> 1;
    const int bn = blockIdx.x * 128;
    const int bm = blockIdx.y * 128;

    const float* apt[4];
    const unsigned* apu[4];
    unsigned lofs4[4];
    #pragma unroll
    for (int i = 0; i < 4; ++i) {
        int f4 = i * 256 + tid, r = f4 >> 3, kq = f4 & 7;
        int gm = bm + r;
        if (Af32) {
            int ar = rowidx ? rowidx[gm] : gm;
            apt[i] = Af32 + (size_t)ar * K + kq * 4;
        } else {
            apu[i] = Apk + (size_t)gm * K + kq * 4;
        }
        lofs4[i] = r * 40 + kq * 4;
    }

    f32x4 acc[4][4];
    #pragma unroll
    for (int i = 0; i < 4; ++i)
        #pragma unroll
        for (int j = 0; j < 4; ++j) acc[i][j] = (f32x4){0.f, 0.f, 0.f, 0.f};

    const int la  = lane & 15;
    const int kg8 = (lane >> 4) * 8;

    for (int k0 = 0; k0 < K; k0 += 32) {
        __syncthreads();
        if (Af32) {
            #pragma unroll
            for (int i = 0; i < 4; ++i) {
                float4 va = *(const float4*)(apt[i] + k0);
                uint2 h, l;
                splitpack(va, h, l);
                *(uint2*)&Ah[lofs4[i]] = h;
                *(uint2*)&Al[lofs4[i]] = l;
            }
        } else {
            #pragma unroll
            for (int i = 0; i < 4; ++i) {
                uint4 p = *(const uint4*)(apu[i] + k0);
                uint2 h, l;
                unpack4(p, h, l);
                *(uint2*)&Ah[lofs4[i]] = h;
                *(uint2*)&Al[lofs4[i]] = l;
            }
        }
        #pragma unroll
        for (int i = 0; i < 2; ++i) {
            int u8 = i * 256 + tid, r = u8 >> 2, c = (u8 & 3) * 8;
            *(ushort8*)&Bh[r * 40 + c] = *(const ushort8*)(Whi + zo + (size_t)(bn + r) * K + k0 + c);
            *(ushort8*)&Bl[r * 40 + c] = *(const ushort8*)(Wlo + zo + (size_t)(bn + r) * K + k0 + c);
        }
        __syncthreads();

        bf16x8 ah[4], al[4];
        #pragma unroll
        for (int mt = 0; mt < 4; ++mt) {
            int row = (wm * 64 + mt * 16 + la) * 40 + kg8;
            ah[mt] = ld8(&Ah[row]);
            al[mt] = ld8(&Al[row]);
        }
        #pragma unroll
        for (int nt = 0; nt < 4; ++nt) {
            int row = (wn * 64 + nt * 16 + la) * 40 + kg8;
            bf16x8 bh = ld8(&Bh[row]);
            bf16x8 bl = ld8(&Bl[row]);
            #pragma unroll
            for (int mt = 0; mt < 4; ++mt)
                acc[mt][nt] = mfma3(acc[mt][nt], ah[mt], al[mt], bh, bl);
        }
    }

    #pragma unroll
    for (int mt = 0; mt < 4; ++mt) {
        int mrow = bm + wm * 64 + mt * 16 + (lane >> 4) * 4;
        #pragma unroll
        for (int nt = 0; nt < 4; ++nt) {
            int n = bn + wn * 64 + nt * 16 + la;
            float bi = bias[n];
            #pragma unroll
            for (int r = 0; r < 4; ++r)
                C[(size_t)(mrow + r) * (3 * H) + n + z * H] = acc[mt][nt][r] + bi;
        }
    }
}

// ---------------------------------------------------------------------------
// Logits GEMM: A packed-split (h1), B pre-split (Wout). N bounds-checked.
// ---------------------------------------------------------------------------
__global__ __launch_bounds__(256) void gemm_logits(
    const unsigned* __restrict__ Apk,
    const unsigned short* __restrict__ Bhi, const unsigned short* __restrict__ Blo,
    const float* __restrict__ bias, float* __restrict__ C, int N, int K)
{
    __shared__ __align__(16) unsigned short Ah[128 * 40];
    __shared__ __align__(16) unsigned short Al[128 * 40];
    __shared__ __align__(16) unsigned short Bh[128 * 40];
    __shared__ __align__(16) unsigned short Bl[128 * 40];

    const int tid  = threadIdx.x;
    const int lane = tid & 63;
    const int wv   = tid >> 6;
    const int wm   = wv & 1, wn = wv >> 1;
    const int bn = blockIdx.x * 128;
    const int bm = blockIdx.y * 128;

    const unsigned* apu[4];
    unsigned lofs4[4];
    #pragma unroll
    for (int i = 0; i < 4; ++i) {
        int f4 = i * 256 + tid, r = f4 >> 3, kq = f4 & 7;
        apu[i] = Apk + (size_t)(bm + r) * K + kq * 4;
        lofs4[i] = r * 40 + kq * 4;
    }

    f32x4 acc[4][4];
    #pragma unroll
    for (int i = 0; i < 4; ++i)
        #pragma unroll
        for (int j = 0; j < 4; ++j) acc[i][j] = (f32x4){0.f, 0.f, 0.f, 0.f};

    const int la  = lane & 15;
    const int kg8 = (lane >> 4) * 8;

    for (int k0 = 0; k0 < K; k0 += 32) {
        __syncthreads();
        #pragma unroll
        for (int i = 0; i < 4; ++i) {
            uint4 p = *(const uint4*)(apu[i] + k0);
            uint2 h, l;
            unpack4(p, h, l);
            *(uint2*)&Ah[lofs4[i]] = h;
            *(uint2*)&Al[lofs4[i]] = l;
        }
        #pragma unroll
        for (int i = 0; i < 2; ++i) {
            int u8 = i * 256 + tid, r = u8 >> 2, c = (u8 & 3) * 8;
            int brow = bn + r;
            int br = (brow < N) ? brow : 0;
            *(ushort8*)&Bh[r * 40 + c] = *(const ushort8*)(Bhi + (size_t)br * K + k0 + c);
            *(ushort8*)&Bl[r * 40 + c] = *(const ushort8*)(Blo + (size_t)br * K + k0 + c);
        }
        __syncthreads();

        bf16x8 ah[4], al[4];
        #pragma unroll
        for (int mt = 0; mt < 4; ++mt) {
            int row = (wm * 64 + mt * 16 + la) * 40 + kg8;
            ah[mt] = ld8(&Ah[row]);
            al[mt] = ld8(&Al[row]);
        }
        #pragma unroll
        for (int nt = 0; nt < 4; ++nt) {
            int row = (wn * 64 + nt * 16 + la) * 40 + kg8;
            bf16x8 bh = ld8(&Bh[row]);
            bf16x8 bl = ld8(&Bl[row]);
            #pragma unroll
            for (int mt = 0; mt < 4; ++mt)
                acc[mt][nt] = mfma3(acc[mt][nt], ah[mt], al[mt], bh, bl);
        }
    }

    #pragma unroll
    for (int mt = 0; mt < 4; ++mt) {
        int mrow = bm + wm * 64 + mt * 16 + (lane >> 4) * 4;
        #pragma unroll
        for (int nt = 0; nt < 4; ++nt) {
            int n = bn + wn * 64 + nt * 16 + la;
            if (n < N) {
                float bi = bias[n];
                #pragma unroll
                for (int r = 0; r < 4; ++r)
                    C[(size_t)(mrow + r) * N + n] = acc[mt][nt][r] + bi;
            }
        }
    }
}

// ---------------------------------------------------------------------------
// Persistent single-layer GRU — R13/R15 structure with packed-split exchange.
// XCD-resident U; 4 independent 64-block m-tile groups; 256 blocks x 1024
// threads (4 waves/SIMD). h / r*h exchanged as u32 = (bf16hi<<16)|bf16lo
// via dword sc0sc1 stores; consumers unpack with v_perm only (no VALU fp).
// Register-carried h + 1-step Wx prefetch.
// ---------------------------------------------------------------------------
__global__ __launch_bounds__(1024, 1) void gru_layer(
    const unsigned short* __restrict__ Uhi, const unsigned short* __restrict__ Ulo,
    const float* __restrict__ Wx, const float* __restrict__ hinit,
    unsigned* __restrict__ hPK, unsigned* __restrict__ rhPK,
    float* __restrict__ hfin, int* cnt)
{
    extern __shared__ char smem[];
    unsigned short* hs_hi = (unsigned short*)smem;       // 16*LDK
    unsigned short* hs_lo = hs_hi + 16 * LDK;
    f32x4* red = (f32x4*)(hs_lo + 16 * LDK);             // 30*64 f32x4

    const int tid  = threadIdx.x;
    const int lane = tid & 63;
    const int kh   = __builtin_amdgcn_readfirstlane(tid >> 6);  // k-16th 0..15
    const int la   = lane & 15;
    const int kg8  = (lane >> 4) * 8;
    const int erow = (lane >> 4) * 4;
    const int trow = tid >> 6;      // staging row 0..15
    const int tq   = tid & 63;      // staging 4-value col group

    const int bid = blockIdx.x;
    const int xcd = bid & 7;
    const int sub = bid >> 3;
    const int grp = sub & 3;
    const int m0  = grp * 16;
    const int j0  = (xcd * 8 + (sub >> 2)) * 16;
    int* gcnt = cnt + grp * 8 * 32;

    const size_t HH = (size_t)H * H;
    const unsigned short* Ur_hi = Uhi;
    const unsigned short* Uz_hi = Uhi + HH;
    const unsigned short* Uh_hi = Uhi + 2 * HH;
    const unsigned short* Ur_lo = Ulo;
    const unsigned short* Uz_lo = Ulo + HH;
    const unsigned short* Uh_lo = Ulo + 2 * HH;

    int gen = 0;
    const int rbase = m0 + erow;

    f32x4 zreg = (f32x4){0.f, 0.f, 0.f, 0.f};
    float hvC[4] = {0.f, 0.f, 0.f, 0.f};
    float wrC[4], wzC[4], whC[4];
    float wrN[4], wzN[4], whN[4];
    if (kh == 0) {
        #pragma unroll
        for (int qq = 0; qq < 4; ++qq) {
            hvC[qq] = hinit[(size_t)(rbase + qq) * H + j0 + la];
            const size_t wb = ((size_t)0 * B + rbase + qq) * (3 * H) + j0 + la;
            wrC[qq] = Wx[wb];
            wzC[qq] = Wx[wb + H];
            whC[qq] = Wx[wb + 2 * H];
        }
    }

    for (int t = 0; t < T; ++t) {
        // ================= phase A: r, z =================
        {
            if (t == 0) {
                const float* hrp = hinit + (size_t)(m0 + trow) * H;
                #pragma unroll
                for (int i = 0; i < 4; ++i) {
                    const int c = (tq + i * 64) * 4;
                    float4 v = *(const float4*)(hrp + c);
                    uint2 h2, l2;
                    splitpack(v, h2, l2);
                    *(uint2*)&hs_hi[trow * LDK + c] = h2;
                    *(uint2*)&hs_lo[trow * LDK + c] = l2;
                }
            } else {
                const unsigned* hrp = hPK + (size_t)(t - 1) * B * H + (size_t)(m0 + trow) * H;
                #pragma unroll
                for (int i = 0; i < 4; ++i) {
                    const int c = (tq + i * 64) * 4;
                    uint4 p = *(const uint4*)(hrp + c);
                    uint2 h2, l2;
                    unpack4(p, h2, l2);
                    *(uint2*)&hs_hi[trow * LDK + c] = h2;
                    *(uint2*)&hs_lo[trow * LDK + c] = l2;
                }
            }
            __syncthreads();
            f32x4 a0 = (f32x4){0.f, 0.f, 0.f, 0.f}, a1 = a0;
            const int kb = kh * 64 + kg8;
            #pragma unroll
            for (int ks = 0; ks < 2; ++ks) {
                const int ko = kb + ks * 32;
                const int ar = la * LDK + ko;
                bf16x8 ah = ld8(&hs_hi[ar]);
                bf16x8 al = ld8(&hs_lo[ar]);
                const size_t ub = (size_t)(j0 + la) * H + ko;
                a0 = mfma3(a0, ah, al, ld8(Ur_hi + ub), ld8(Ur_lo + ub));
                a1 = mfma3(a1, ah, al, ld8(Uz_hi + ub), ld8(Uz_lo + ub));
            }
            if (kh) {
                red[((kh - 1) * 2 + 0) * 64 + lane] = a0;
                red[((kh - 1) * 2 + 1) * 64 + lane] = a1;
            }
            __syncthreads();
            if (kh == 0) {
                #pragma unroll
                for (int w = 0; w < 15; ++w) {
                    a0 += red[(w * 2 + 0) * 64 + lane];
                    a1 += red[(w * 2 + 1) * 64 + lane];
                }
                #pragma unroll
                for (int qq = 0; qq < 4; ++qq) {
                    float rg = 1.f / (1.f + __expf(-(a0[qq] + wrC[qq])));
                    zreg[qq] = 1.f / (1.f + __expf(-(a1[qq] + wzC[qq])));
                    unsigned pk = pack1(rg * hvC[qq]);
                    store_f32_sc((float*)(rhPK + ((size_t)t * B + rbase + qq) * H + j0 + la),
                                 __uint_as_float(pk));
                }
            }
        }
        gridbar_grp(gcnt, ++gen);

        // ================= phase B: h~ and update =================
        {
            if (kh == 0 && t + 1 < T) {
                #pragma unroll
                for (int qq = 0; qq < 4; ++qq) {
                    const size_t wb = ((size_t)(t + 1) * B + rbase + qq) * (3 * H) + j0 + la;
                    wrN[qq] = Wx[wb];
                    wzN[qq] = Wx[wb + H];
                    whN[qq] = Wx[wb + 2 * H];
                }
            }
            {
                const unsigned* rrp = rhPK + (size_t)t * B * H + (size_t)(m0 + trow) * H;
                #pragma unroll
                for (int i = 0; i < 4; ++i) {
                    const int c = (tq + i * 64) * 4;
                    uint4 p = *(const uint4*)(rrp + c);
                    uint2 h2, l2;
                    unpack4(p, h2, l2);
                    *(uint2*)&hs_hi[trow * LDK + c] = h2;
                    *(uint2*)&hs_lo[trow * LDK + c] = l2;
                }
            }
            __syncthreads();
            f32x4 a = (f32x4){0.f, 0.f, 0.f, 0.f};
            const int kb = kh * 64 + kg8;
            #pragma unroll
            for (int ks = 0; ks < 2; ++ks) {
                const int ko = kb + ks * 32;
                const int ar = la * LDK + ko;
                const size_t ub = (size_t)(j0 + la) * H + ko;
                a = mfma3(a, ld8(&hs_hi[ar]), ld8(&hs_lo[ar]),
                          ld8(Uh_hi + ub), ld8(Uh_lo + ub));
            }
            if (kh) red[(kh - 1) * 64 + lane] = a;
            __syncthreads();
            if (kh == 0) {
                #pragma unroll
                for (int w = 0; w < 15; ++w) a += red[w * 64 + lane];
                #pragma unroll
                for (int qq = 0; qq < 4; ++qq) {
                    float ht = tanhf(a[qq] + whC[qq]);
                    float hn = (1.f - zreg[qq]) * hvC[qq] + zreg[qq] * ht;
                    unsigned pk = pack1(hn);
                    store_f32_sc((float*)(hPK + ((size_t)t * B + rbase + qq) * H + j0 + la),
                                 __uint_as_float(pk));
                    if (t == T - 1)
                        store_f32_sc(hfin + (size_t)(rbase + qq) * H + j0 + la, hn);
                    hvC[qq] = hn;
                    wrC[qq] = wrN[qq];
                    wzC[qq] = wzN[qq];
                    whC[qq] = whN[qq];
                }
            }
        }
        gridbar_grp(gcnt, ++gen);
    }
}

// ---------------------------------------------------------------------------
extern "C" void kernel_launch(void* const* d_in, const int* in_sizes, int n_in,
                              void* d_out, int out_size, void* d_ws, size_t ws_size,
                              hipStream_t stream)
{
    const int*   tok    = (const int*)d_in[0];
    const float* hidden = (const float*)d_in[1];
    const float* emb    = (const float*)d_in[2];
    const float* Wr0 = (const float*)d_in[3],  *br0 = (const float*)d_in[4];
    const float* Wz0 = (const float*)d_in[5],  *bz0 = (const float*)d_in[6];
    const float* Wh0 = (const float*)d_in[7],  *bh0 = (const float*)d_in[8];
    const float* Ur0 = (const float*)d_in[9],  *Uz0 = (const float*)d_in[10], *Uh0 = (const float*)d_in[11];
    const float* Wr1 = (const float*)d_in[12], *br1 = (const float*)d_in[13];
    const float* Wz1 = (const float*)d_in[14], *bz1 = (const float*)d_in[15];
    const float* Wh1 = (const float*)d_in[16], *bh1 = (const float*)d_in[17];
    const float* Ur1 = (const float*)d_in[18], *Uz1 = (const float*)d_in[19], *Uh1 = (const float*)d_in[20];
    const float* Wout = (const float*)d_in[21], *bout = (const float*)d_in[22];
    float* out = (float*)d_out;

    const size_t HH = (size_t)H * H;
    const size_t HE = (size_t)H * E;
    const size_t TBH = (size_t)T * B * H;
    const size_t VH = (size_t)V * H;

    float* ws = (float*)d_ws;
    float* Wx = ws;                                      // T*B*3H fp32
    unsigned* h0PK  = (unsigned*)(Wx + 3 * TBH);         // TBH u32 packed
    unsigned* rh0PK = h0PK  + TBH;
    unsigned* h1PK  = rh0PK + TBH;
    unsigned* rh1PK = h1PK  + TBH;
    unsigned short* u16 = (unsigned short*)(rh1PK + TBH);
    unsigned short* U0hi = u16;    u16 += 3 * HH;
    unsigned short* U0lo = u16;    u16 += 3 * HH;
    unsigned short* U1hi = u16;    u16 += 3 * HH;
    unsigned short* U1lo = u16;    u16 += 3 * HH;
    unsigned short* W1hi = u16;    u16 += 3 * HH;
    unsigned short* W1lo = u16;    u16 += 3 * HH;
    unsigned short* W0hi = u16;    u16 += 3 * HE;
    unsigned short* W0lo = u16;    u16 += 3 * HE;
    unsigned short* Wouthi = u16;  u16 += VH;
    unsigned short* Woutlo = u16;  u16 += VH;
    int* cnt0 = (int*)u16;
    int* cnt1 = cnt0 + 4 * 8 * 32;

    static bool attr_set = false;
    if (!attr_set) {
        (void)hipFuncSetAttribute((const void*)gru_layer,
                                  hipFuncAttributeMaxDynamicSharedMemorySize, 96768);
        attr_set = true;
    }

    (void)hipMemsetAsync(cnt0, 0, 2 * 4 * 8 * 32 * sizeof(int), stream);

    // ---- fused prepass split (13 segments, one launch) ----
    const unsigned nU = (unsigned)(HH / 4), nW0 = (unsigned)(HE / 4);
    const unsigned nWout = (unsigned)(VH / 4);
    SplitTab tab;
    unsigned acc = 0;
    const float* srcs[13] = {Ur0, Uz0, Uh0, Ur1, Uz1, Uh1, Wr1, Wz1, Wh1,
                             Wr0, Wz0, Wh0, Wout};
    unsigned short* his[13] = {U0hi, U0hi + HH, U0hi + 2 * HH, U1hi, U1hi + HH, U1hi + 2 * HH,
                               W1hi, W1hi + HH, W1hi + 2 * HH,
                               W0hi, W0hi + HE, W0hi + 2 * HE, Wouthi};
    unsigned short* los[13] = {U0lo, U0lo + HH, U0lo + 2 * HH, U1lo, U1lo + HH, U1lo + 2 * HH,
                               W1lo, W1lo + HH, W1lo + 2 * HH,
                               W0lo, W0lo + HE, W0lo + 2 * HE, Woutlo};
    unsigned cnts[13] = {nU, nU, nU, nU, nU, nU, nU, nU, nU, nW0, nW0, nW0, nWout};
    for (int i = 0; i < 13; ++i) {
        acc += cnts[i];
        tab.s[i] = {srcs[i], his[i], los[i], acc};
    }
    split_all<<<acc / 256, 256, 0, stream>>>(tab);

    // ---- Wx(L0) = emb[tok] @ W0^T + b (fp32 A, gather fused) ----
    gemm_wx3h<<<dim3(H / 128, T * B / 128, 3), 256, 0, stream>>>(
        emb, nullptr, W0hi, W0lo, br0, bz0, bh0, Wx, tok, E);

    gru_layer<<<NWG, 1024, 96768, stream>>>(U0hi, U0lo, Wx, hidden,
                                            h0PK, rh0PK, out + (size_t)T * B * V, cnt0);

    // ---- Wx(L1) = h0 @ W1^T + b (packed-split A) ----
    gemm_wx3h<<<dim3(H / 128, T * B / 128, 3), 256, 0, stream>>>(
        nullptr, h0PK, W1hi, W1lo, br1, bz1, bh1, Wx, nullptr, H);

    gru_layer<<<NWG, 1024, 96768, stream>>>(U1hi, U1lo, Wx, hidden + (size_t)B * H,
                                            h1PK, rh1PK,
                                            out + (size_t)T * B * V + (size_t)B * H, cnt1);

    // ---- logits = h1 @ Wout^T + bout (packed-split A) ----
    gemm_logits<<<dim3((V + 127) / 128, T * B / 128), 256, 0, stream>>>(
        h1PK, Wouthi, Woutlo, bout, out, V, H);
}

// Round 18
// 3281.594 us; speedup vs baseline: 1.1345x; 1.0094x over previous
//
#include <hip/hip_runtime.h>
#include <hip/hip_bf16.h>
#include <math.h>

#define V 10000
#define E 512
#define H 1024
#define T 128
#define B 64
#define NWG 256
#define LDK 1032   // LDS row stride in ushorts (2064 B)

typedef __bf16 bf16x8 __attribute__((ext_vector_type(8)));
typedef float f32x4 __attribute__((ext_vector_type(4)));
typedef unsigned short ushort8 __attribute__((ext_vector_type(8)));

// ---------------------------------------------------------------------------
// Cache-bypassing (coherent-at-MALL) access helpers (validated R4-R17).
// ---------------------------------------------------------------------------
__device__ __forceinline__ void store_f32_sc(float* p, float v) {
    asm volatile("global_store_dword %0, %1, off sc0 sc1" :: "v"(p), "v"(v) : "memory");
}
__device__ __forceinline__ void store_i32_sc(int* p, int v) {
    asm volatile("global_store_dword %0, %1, off sc0 sc1" :: "v"(p), "v"(v) : "memory");
}
__device__ __forceinline__ int load_i32_sc(const int* p) {
    int r;
    asm volatile("global_load_dword %0, %1, off sc0 sc1\n\ts_waitcnt vmcnt(0)"
                 : "=v"(r) : "v"(p) : "memory");
    return r;
}

// ---------------------------------------------------------------------------
// Flag-per-block group barrier (no RMW): 64 blocks/group; each block stores
// gen to its own 16B-strided slot; threads 0-63 poll one flag each
// (wave-parallel single load per iteration). Ordering: vmcnt(0)+syncthreads
// drains data stores before the flag store issues (validated protocol R4+).
// ---------------------------------------------------------------------------
__device__ __forceinline__ void gridbar_grp(int* flags, int myidx, int gen) {
    asm volatile("s_waitcnt vmcnt(0)" ::: "memory");
    __syncthreads();
    if (threadIdx.x == 0)
        store_i32_sc(flags + myidx * 4, gen);
    if (threadIdx.x < 64) {
        while (load_i32_sc(flags + threadIdx.x * 4) < gen)
            __builtin_amdgcn_s_sleep(1);
    }
    __syncthreads();
}

// ---------------------------------------------------------------------------
// Split: fp32 -> truncated-hi bf16 + residual-lo bf16 (deterministic).
// ---------------------------------------------------------------------------
__device__ inline void splitpack(float4 v, uint2& hi, uint2& lo) {
    unsigned u0 = __float_as_uint(v.x), u1 = __float_as_uint(v.y);
    unsigned u2 = __float_as_uint(v.z), u3 = __float_as_uint(v.w);
    hi.x = __builtin_amdgcn_perm(u1, u0, 0x07060302u);
    hi.y = __builtin_amdgcn_perm(u3, u2, 0x07060302u);
    float l0 = v.x - __uint_as_float(u0 & 0xFFFF0000u);
    float l1 = v.y - __uint_as_float(u1 & 0xFFFF0000u);
    float l2 = v.z - __uint_as_float(u2 & 0xFFFF0000u);
    float l3 = v.w - __uint_as_float(u3 & 0xFFFF0000u);
    lo.x = __builtin_amdgcn_perm(__float_as_uint(l1), __float_as_uint(l0), 0x07060302u);
    lo.y = __builtin_amdgcn_perm(__float_as_uint(l3), __float_as_uint(l2), 0x07060302u);
}
// packed u32 = (hi16 << 16) | bf16(residual)
__device__ __forceinline__ unsigned pack1(float f) {
    unsigned u = __float_as_uint(f);
    float l = f - __uint_as_float(u & 0xFFFF0000u);
    return (u & 0xFFFF0000u) | (__float_as_uint(l) >> 16);
}
// unpack 4 packed values -> 4 hi ushorts (uint2) + 4 lo ushorts (uint2)
__device__ __forceinline__ void unpack4(uint4 p, uint2& hi, uint2& lo) {
    hi.x = __builtin_amdgcn_perm(p.y, p.x, 0x07060302u);
    hi.y = __builtin_amdgcn_perm(p.w, p.z, 0x07060302u);
    lo.x = __builtin_amdgcn_perm(p.y, p.x, 0x05040100u);
    lo.y = __builtin_amdgcn_perm(p.w, p.z, 0x05040100u);
}

__device__ __forceinline__ bf16x8 ld8(const unsigned short* p) {
    return __builtin_bit_cast(bf16x8, *(const ushort8*)p);
}
__device__ __forceinline__ f32x4 mfma3(f32x4 acc, bf16x8 ah, bf16x8 al,
                                       bf16x8 bh, bf16x8 bl) {
    acc = __builtin_amdgcn_mfma_f32_16x16x32_bf16(ah, bh, acc, 0, 0, 0);
    acc = __builtin_amdgcn_mfma_f32_16x16x32_bf16(al, bh, acc, 0, 0, 0);
    acc = __builtin_amdgcn_mfma_f32_16x16x32_bf16(ah, bl, acc, 0, 0, 0);
    return acc;
}

// ---------------------------------------------------------------------------
// Fused prepass: split all weights into bf16 hi/lo (one launch, 13 segments).
// ---------------------------------------------------------------------------
struct SplitSeg { const float* src; unsigned short* hi; unsigned short* lo; unsigned end; };
struct SplitTab { SplitSeg s[13]; };

__global__ __launch_bounds__(256) void split_all(SplitTab tab) {
    unsigned idx = blockIdx.x * 256 + threadIdx.x;
    unsigned base = 0;
    #pragma unroll
    for (int i = 0; i < 13; ++i) {
        if (idx < tab.s[i].end) {
            unsigned off = idx - base;
            float4 v = ((const float4*)tab.s[i].src)[off];
            uint2 h, l;
            splitpack(v, h, l);
            ((uint2*)tab.s[i].hi)[off] = h;
            ((uint2*)tab.s[i].lo)[off] = l;
            return;
        }
        base = tab.s[i].end;
    }
}

// ---------------------------------------------------------------------------
// Batched 3-gate Wx GEMM: B pre-split bf16. A either fp32 with gather (emb)
// or packed-split u32 (h0). gridDim.z = 3 selects gate; N = H exact.
// ---------------------------------------------------------------------------
__global__ __launch_bounds__(256) void gemm_wx3h(
    const float* __restrict__ Af32, const unsigned* __restrict__ Apk,
    const unsigned short* __restrict__ Whi, const unsigned short* __restrict__ Wlo,
    const float* __restrict__ b0, const float* __restrict__ b1, const float* __restrict__ b2,
    float* __restrict__ C, const int* __restrict__ rowidx, int K)
{
    __shared__ __align__(16) unsigned short Ah[128 * 40];
    __shared__ __align__(16) unsigned short Al[128 * 40];
    __shared__ __align__(16) unsigned short Bh[128 * 40];
    __shared__ __align__(16) unsigned short Bl[128 * 40];

    const int z = blockIdx.z;
    const float* __restrict__ bias = (z == 0) ? b0 : (z == 1) ? b1 : b2;
    const size_t zo = (size_t)z * H * K;

    const int tid  = threadIdx.x;
    const int lane = tid & 63;
    const int wv   = tid >> 6;
    const int wm   = wv & 1, wn = wv >> 1;
    const int bn = blockIdx.x * 128;
    const int bm = blockIdx.y * 128;

    const float* apt[4];
    const unsigned* apu[4];
    unsigned lofs4[4];
    #pragma unroll
    for (int i = 0; i < 4; ++i) {
        int f4 = i * 256 + tid, r = f4 >> 3, kq = f4 & 7;
        int gm = bm + r;
        if (Af32) {
            int ar = rowidx ? rowidx[gm] : gm;
            apt[i] = Af32 + (size_t)ar * K + kq * 4;
        } else {
            apu[i] = Apk + (size_t)gm * K + kq * 4;
        }
        lofs4[i] = r * 40 + kq * 4;
    }

    f32x4 acc[4][4];
    #pragma unroll
    for (int i = 0; i < 4; ++i)
        #pragma unroll
        for (int j = 0; j < 4; ++j) acc[i][j] = (f32x4){0.f, 0.f, 0.f, 0.f};

    const int la  = lane & 15;
    const int kg8 = (lane >> 4) * 8;

    for (int k0 = 0; k0 < K; k0 += 32) {
        __syncthreads();
        if (Af32) {
            #pragma unroll
            for (int i = 0; i < 4; ++i) {
                float4 va = *(const float4*)(apt[i] + k0);
                uint2 h, l;
                splitpack(va, h, l);
                *(uint2*)&Ah[lofs4[i]] = h;
                *(uint2*)&Al[lofs4[i]] = l;
            }
        } else {
            #pragma unroll
            for (int i = 0; i < 4; ++i) {
                uint4 p = *(const uint4*)(apu[i] + k0);
                uint2 h, l;
                unpack4(p, h, l);
                *(uint2*)&Ah[lofs4[i]] = h;
                *(uint2*)&Al[lofs4[i]] = l;
            }
        }
        #pragma unroll
        for (int i = 0; i < 2; ++i) {
            int u8 = i * 256 + tid, r = u8 >> 2, c = (u8 & 3) * 8;
            *(ushort8*)&Bh[r * 40 + c] = *(const ushort8*)(Whi + zo + (size_t)(bn + r) * K + k0 + c);
            *(ushort8*)&Bl[r * 40 + c] = *(const ushort8*)(Wlo + zo + (size_t)(bn + r) * K + k0 + c);
        }
        __syncthreads();

        bf16x8 ah[4], al[4];
        #pragma unroll
        for (int mt = 0; mt < 4; ++mt) {
            int row = (wm * 64 + mt * 16 + la) * 40 + kg8;
            ah[mt] = ld8(&Ah[row]);
            al[mt] = ld8(&Al[row]);
        }
        #pragma unroll
        for (int nt = 0; nt < 4; ++nt) {
            int row = (wn * 64 + nt * 16 + la) * 40 + kg8;
            bf16x8 bh = ld8(&Bh[row]);
            bf16x8 bl = ld8(&Bl[row]);
            #pragma unroll
            for (int mt = 0; mt < 4; ++mt)
                acc[mt][nt] = mfma3(acc[mt][nt], ah[mt], al[mt], bh, bl);
        }
    }

    #pragma unroll
    for (int mt = 0; mt < 4; ++mt) {
        int mrow = bm + wm * 64 + mt * 16 + (lane >> 4) * 4;
        #pragma unroll
        for (int nt = 0; nt < 4; ++nt) {
            int n = bn + wn * 64 + nt * 16 + la;
            float bi = bias[n];
            #pragma unroll
            for (int r = 0; r < 4; ++r)
                C[(size_t)(mrow + r) * (3 * H) + n + z * H] = acc[mt][nt][r] + bi;
        }
    }
}

// ---------------------------------------------------------------------------
// Logits GEMM: A packed-split (h1), B pre-split (Wout). N bounds-checked.
// ---------------------------------------------------------------------------
__global__ __launch_bounds__(256) void gemm_logits(
    const unsigned* __restrict__ Apk,
    const unsigned short* __restrict__ Bhi, const unsigned short* __restrict__ Blo,
    const float* __restrict__ bias, float* __restrict__ C, int N, int K)
{
    __shared__ __align__(16) unsigned short Ah[128 * 40];
    __shared__ __align__(16) unsigned short Al[128 * 40];
    __shared__ __align__(16) unsigned short Bh[128 * 40];
    __shared__ __align__(16) unsigned short Bl[128 * 40];

    const int tid  = threadIdx.x;
    const int lane = tid & 63;
    const int wv   = tid >> 6;
    const int wm   = wv & 1, wn = wv >> 1;
    const int bn = blockIdx.x * 128;
    const int bm = blockIdx.y * 128;

    const unsigned* apu[4];
    unsigned lofs4[4];
    #pragma unroll
    for (int i = 0; i < 4; ++i) {
        int f4 = i * 256 + tid, r = f4 >> 3, kq = f4 & 7;
        apu[i] = Apk + (size_t)(bm + r) * K + kq * 4;
        lofs4[i] = r * 40 + kq * 4;
    }

    f32x4 acc[4][4];
    #pragma unroll
    for (int i = 0; i < 4; ++i)
        #pragma unroll
        for (int j = 0; j < 4; ++j) acc[i][j] = (f32x4){0.f, 0.f, 0.f, 0.f};

    const int la  = lane & 15;
    const int kg8 = (lane >> 4) * 8;

    for (int k0 = 0; k0 < K; k0 += 32) {
        __syncthreads();
        #pragma unroll
        for (int i = 0; i < 4; ++i) {
            uint4 p = *(const uint4*)(apu[i] + k0);
            uint2 h, l;
            unpack4(p, h, l);
            *(uint2*)&Ah[lofs4[i]] = h;
            *(uint2*)&Al[lofs4[i]] = l;
        }
        #pragma unroll
        for (int i = 0; i < 2; ++i) {
            int u8 = i * 256 + tid, r = u8 >> 2, c = (u8 & 3) * 8;
            int brow = bn + r;
            int br = (brow < N) ? brow : 0;
            *(ushort8*)&Bh[r * 40 + c] = *(const ushort8*)(Bhi + (size_t)br * K + k0 + c);
            *(ushort8*)&Bl[r * 40 + c] = *(const ushort8*)(Blo + (size_t)br * K + k0 + c);
        }
        __syncthreads();

        bf16x8 ah[4], al[4];
        #pragma unroll
        for (int mt = 0; mt < 4; ++mt) {
            int row = (wm * 64 + mt * 16 + la) * 40 + kg8;
            ah[mt] = ld8(&Ah[row]);
            al[mt] = ld8(&Al[row]);
        }
        #pragma unroll
        for (int nt = 0; nt < 4; ++nt) {
            int row = (wn * 64 + nt * 16 + la) * 40 + kg8;
            bf16x8 bh = ld8(&Bh[row]);
            bf16x8 bl = ld8(&Bl[row]);
            #pragma unroll
            for (int mt = 0; mt < 4; ++mt)
                acc[mt][nt] = mfma3(acc[mt][nt], ah[mt], al[mt], bh, bl);
        }
    }

    #pragma unroll
    for (int mt = 0; mt < 4; ++mt) {
        int mrow = bm + wm * 64 + mt * 16 + (lane >> 4) * 4;
        #pragma unroll
        for (int nt = 0; nt < 4; ++nt) {
            int n = bn + wn * 64 + nt * 16 + la;
            if (n < N) {
                float bi = bias[n];
                #pragma unroll
                for (int r = 0; r < 4; ++r)
                    C[(size_t)(mrow + r) * N + n] = acc[mt][nt][r] + bi;
            }
        }
    }
}

// ---------------------------------------------------------------------------
// Persistent single-layer GRU — R17 structure + flag-per-block barrier.
// XCD-resident U; 4 independent 64-block m-tile groups; 256 blocks x 1024
// threads (4 waves/SIMD). Packed u32 exchange; register-carried h;
// 1-step Wx prefetch.
// ---------------------------------------------------------------------------
__global__ __launch_bounds__(1024, 1) void gru_layer(
    const unsigned short* __restrict__ Uhi, const unsigned short* __restrict__ Ulo,
    const float* __restrict__ Wx, const float* __restrict__ hinit,
    unsigned* __restrict__ hPK, unsigned* __restrict__ rhPK,
    float* __restrict__ hfin, int* cnt)
{
    extern __shared__ char smem[];
    unsigned short* hs_hi = (unsigned short*)smem;       // 16*LDK
    unsigned short* hs_lo = hs_hi + 16 * LDK;
    f32x4* red = (f32x4*)(hs_lo + 16 * LDK);             // 30*64 f32x4

    const int tid  = threadIdx.x;
    const int lane = tid & 63;
    const int kh   = __builtin_amdgcn_readfirstlane(tid >> 6);  // k-16th 0..15
    const int la   = lane & 15;
    const int kg8  = (lane >> 4) * 8;
    const int erow = (lane >> 4) * 4;
    const int trow = tid >> 6;      // staging row 0..15
    const int tq   = tid & 63;      // staging 4-value col group

    const int bid = blockIdx.x;
    const int xcd = bid & 7;
    const int sub = bid >> 3;
    const int grp = sub & 3;
    const int m0  = grp * 16;
    const int j0  = (xcd * 8 + (sub >> 2)) * 16;
    const int myidx = xcd * 8 + (sub >> 2);              // block index in group
    int* gflags = cnt + grp * 256;                       // 64 flags * 4-int stride

    const size_t HH = (size_t)H * H;
    const unsigned short* Ur_hi = Uhi;
    const unsigned short* Uz_hi = Uhi + HH;
    const unsigned short* Uh_hi = Uhi + 2 * HH;
    const unsigned short* Ur_lo = Ulo;
    const unsigned short* Uz_lo = Ulo + HH;
    const unsigned short* Uh_lo = Ulo + 2 * HH;

    int gen = 0;
    const int rbase = m0 + erow;

    f32x4 zreg = (f32x4){0.f, 0.f, 0.f, 0.f};
    float hvC[4] = {0.f, 0.f, 0.f, 0.f};
    float wrC[4], wzC[4], whC[4];
    float wrN[4], wzN[4], whN[4];
    if (kh == 0) {
        #pragma unroll
        for (int qq = 0; qq < 4; ++qq) {
            hvC[qq] = hinit[(size_t)(rbase + qq) * H + j0 + la];
            const size_t wb = ((size_t)0 * B + rbase + qq) * (3 * H) + j0 + la;
            wrC[qq] = Wx[wb];
            wzC[qq] = Wx[wb + H];
            whC[qq] = Wx[wb + 2 * H];
        }
    }

    for (int t = 0; t < T; ++t) {
        // ================= phase A: r, z =================
        {
            if (t == 0) {
                const float* hrp = hinit + (size_t)(m0 + trow) * H;
                #pragma unroll
                for (int i = 0; i < 4; ++i) {
                    const int c = (tq + i * 64) * 4;
                    float4 v = *(const float4*)(hrp + c);
                    uint2 h2, l2;
                    splitpack(v, h2, l2);
                    *(uint2*)&hs_hi[trow * LDK + c] = h2;
                    *(uint2*)&hs_lo[trow * LDK + c] = l2;
                }
            } else {
                const unsigned* hrp = hPK + (size_t)(t - 1) * B * H + (size_t)(m0 + trow) * H;
                #pragma unroll
                for (int i = 0; i < 4; ++i) {
                    const int c = (tq + i * 64) * 4;
                    uint4 p = *(const uint4*)(hrp + c);
                    uint2 h2, l2;
                    unpack4(p, h2, l2);
                    *(uint2*)&hs_hi[trow * LDK + c] = h2;
                    *(uint2*)&hs_lo[trow * LDK + c] = l2;
                }
            }
            __syncthreads();
            f32x4 a0 = (f32x4){0.f, 0.f, 0.f, 0.f}, a1 = a0;
            const int kb = kh * 64 + kg8;
            #pragma unroll
            for (int ks = 0; ks < 2; ++ks) {
                const int ko = kb + ks * 32;
                const int ar = la * LDK + ko;
                bf16x8 ah = ld8(&hs_hi[ar]);
                bf16x8 al = ld8(&hs_lo[ar]);
                const size_t ub = (size_t)(j0 + la) * H + ko;
                a0 = mfma3(a0, ah, al, ld8(Ur_hi + ub), ld8(Ur_lo + ub));
                a1 = mfma3(a1, ah, al, ld8(Uz_hi + ub), ld8(Uz_lo + ub));
            }
            if (kh) {
                red[((kh - 1) * 2 + 0) * 64 + lane] = a0;
                red[((kh - 1) * 2 + 1) * 64 + lane] = a1;
            }
            __syncthreads();
            if (kh == 0) {
                #pragma unroll
                for (int w = 0; w < 15; ++w) {
                    a0 += red[(w * 2 + 0) * 64 + lane];
                    a1 += red[(w * 2 + 1) * 64 + lane];
                }
                #pragma unroll
                for (int qq = 0; qq < 4; ++qq) {
                    float rg = 1.f / (1.f + __expf(-(a0[qq] + wrC[qq])));
                    zreg[qq] = 1.f / (1.f + __expf(-(a1[qq] + wzC[qq])));
                    unsigned pk = pack1(rg * hvC[qq]);
                    store_f32_sc((float*)(rhPK + ((size_t)t * B + rbase + qq) * H + j0 + la),
                                 __uint_as_float(pk));
                }
            }
        }
        gridbar_grp(gflags, myidx, ++gen);

        // ================= phase B: h~ and update =================
        {
            if (kh == 0 && t + 1 < T) {
                #pragma unroll
                for (int qq = 0; qq < 4; ++qq) {
                    const size_t wb = ((size_t)(t + 1) * B + rbase + qq) * (3 * H) + j0 + la;
                    wrN[qq] = Wx[wb];
                    wzN[qq] = Wx[wb + H];
                    whN[qq] = Wx[wb + 2 * H];
                }
            }
            {
                const unsigned* rrp = rhPK + (size_t)t * B * H + (size_t)(m0 + trow) * H;
                #pragma unroll
                for (int i = 0; i < 4; ++i) {
                    const int c = (tq + i * 64) * 4;
                    uint4 p = *(const uint4*)(rrp + c);
                    uint2 h2, l2;
                    unpack4(p, h2, l2);
                    *(uint2*)&hs_hi[trow * LDK + c] = h2;
                    *(uint2*)&hs_lo[trow * LDK + c] = l2;
                }
            }
            __syncthreads();
            f32x4 a = (f32x4){0.f, 0.f, 0.f, 0.f};
            const int kb = kh * 64 + kg8;
            #pragma unroll
            for (int ks = 0; ks < 2; ++ks) {
                const int ko = kb + ks * 32;
                const int ar = la * LDK + ko;
                const size_t ub = (size_t)(j0 + la) * H + ko;
                a = mfma3(a, ld8(&hs_hi[ar]), ld8(&hs_lo[ar]),
                          ld8(Uh_hi + ub), ld8(Uh_lo + ub));
            }
            if (kh) red[(kh - 1) * 64 + lane] = a;
            __syncthreads();
            if (kh == 0) {
                #pragma unroll
                for (int w = 0; w < 15; ++w) a += red[w * 64 + lane];
                #pragma unroll
                for (int qq = 0; qq < 4; ++qq) {
                    float ht = tanhf(a[qq] + whC[qq]);
                    float hn = (1.f - zreg[qq]) * hvC[qq] + zreg[qq] * ht;
                    unsigned pk = pack1(hn);
                    store_f32_sc((float*)(hPK + ((size_t)t * B + rbase + qq) * H + j0 + la),
                                 __uint_as_float(pk));
                    if (t == T - 1)
                        store_f32_sc(hfin + (size_t)(rbase + qq) * H + j0 + la, hn);
                    hvC[qq] = hn;
                    wrC[qq] = wrN[qq];
                    wzC[qq] = wzN[qq];
                    whC[qq] = whN[qq];
                }
            }
        }
        gridbar_grp(gflags, myidx, ++gen);
    }
}

// ---------------------------------------------------------------------------
extern "C" void kernel_launch(void* const* d_in, const int* in_sizes, int n_in,
                              void* d_out, int out_size, void* d_ws, size_t ws_size,
                              hipStream_t stream)
{
    const int*   tok    = (const int*)d_in[0];
    const float* hidden = (const float*)d_in[1];
    const float* emb    = (const float*)d_in[2];
    const float* Wr0 = (const float*)d_in[3],  *br0 = (const float*)d_in[4];
    const float* Wz0 = (const float*)d_in[5],  *bz0 = (const float*)d_in[6];
    const float* Wh0 = (const float*)d_in[7],  *bh0 = (const float*)d_in[8];
    const float* Ur0 = (const float*)d_in[9],  *Uz0 = (const float*)d_in[10], *Uh0 = (const float*)d_in[11];
    const float* Wr1 = (const float*)d_in[12], *br1 = (const float*)d_in[13];
    const float* Wz1 = (const float*)d_in[14], *bz1 = (const float*)d_in[15];
    const float* Wh1 = (const float*)d_in[16], *bh1 = (const float*)d_in[17];
    const float* Ur1 = (const float*)d_in[18], *Uz1 = (const float*)d_in[19], *Uh1 = (const float*)d_in[20];
    const float* Wout = (const float*)d_in[21], *bout = (const float*)d_in[22];
    float* out = (float*)d_out;

    const size_t HH = (size_t)H * H;
    const size_t HE = (size_t)H * E;
    const size_t TBH = (size_t)T * B * H;
    const size_t VH = (size_t)V * H;

    float* ws = (float*)d_ws;
    float* Wx = ws;                                      // T*B*3H fp32
    unsigned* h0PK  = (unsigned*)(Wx + 3 * TBH);         // TBH u32 packed
    unsigned* rh0PK = h0PK  + TBH;
    unsigned* h1PK  = rh0PK + TBH;
    unsigned* rh1PK = h1PK  + TBH;
    unsigned short* u16 = (unsigned short*)(rh1PK + TBH);
    unsigned short* U0hi = u16;    u16 += 3 * HH;
    unsigned short* U0lo = u16;    u16 += 3 * HH;
    unsigned short* U1hi = u16;    u16 += 3 * HH;
    unsigned short* U1lo = u16;    u16 += 3 * HH;
    unsigned short* W1hi = u16;    u16 += 3 * HH;
    unsigned short* W1lo = u16;    u16 += 3 * HH;
    unsigned short* W0hi = u16;    u16 += 3 * HE;
    unsigned short* W0lo = u16;    u16 += 3 * HE;
    unsigned short* Wouthi = u16;  u16 += VH;
    unsigned short* Woutlo = u16;  u16 += VH;
    int* cnt0 = (int*)u16;                               // 4 grp * 64 flags * 4
    int* cnt1 = cnt0 + 4 * 64 * 4;

    static bool attr_set = false;
    if (!attr_set) {
        (void)hipFuncSetAttribute((const void*)gru_layer,
                                  hipFuncAttributeMaxDynamicSharedMemorySize, 96768);
        attr_set = true;
    }

    (void)hipMemsetAsync(cnt0, 0, 2 * 4 * 64 * 4 * sizeof(int), stream);

    // ---- fused prepass split (13 segments, one launch) ----
    const unsigned nU = (unsigned)(HH / 4), nW0 = (unsigned)(HE / 4);
    const unsigned nWout = (unsigned)(VH / 4);
    SplitTab tab;
    unsigned acc = 0;
    const float* srcs[13] = {Ur0, Uz0, Uh0, Ur1, Uz1, Uh1, Wr1, Wz1, Wh1,
                             Wr0, Wz0, Wh0, Wout};
    unsigned short* his[13] = {U0hi, U0hi + HH, U0hi + 2 * HH, U1hi, U1hi + HH, U1hi + 2 * HH,
                               W1hi, W1hi + HH, W1hi + 2 * HH,
                               W0hi, W0hi + HE, W0hi + 2 * HE, Wouthi};
    unsigned short* los[13] = {U0lo, U0lo + HH, U0lo + 2 * HH, U1lo, U1lo + HH, U1lo + 2 * HH,
                               W1lo, W1lo + HH, W1lo + 2 * HH,
                               W0lo, W0lo + HE, W0lo + 2 * HE, Woutlo};
    unsigned cnts[13] = {nU, nU, nU, nU, nU, nU, nU, nU, nU, nW0, nW0, nW0, nWout};
    for (int i = 0; i < 13; ++i) {
        acc += cnts[i];
        tab.s[i] = {srcs[i], his[i], los[i], acc};
    }
    split_all<<<acc / 256, 256, 0, stream>>>(tab);

    // ---- Wx(L0) = emb[tok] @ W0^T + b (fp32 A, gather fused) ----
    gemm_wx3h<<<dim3(H / 128, T * B / 128, 3), 256, 0, stream>>>(
        emb, nullptr, W0hi, W0lo, br0, bz0, bh0, Wx, tok, E);

    gru_layer<<<NWG, 1024, 96768, stream>>>(U0hi, U0lo, Wx, hidden,
                                            h0PK, rh0PK, out + (size_t)T * B * V, cnt0);

    // ---- Wx(L1) = h0 @ W1^T + b (packed-split A) ----
    gemm_wx3h<<<dim3(H / 128, T * B / 128, 3), 256, 0, stream>>>(
        nullptr, h0PK, W1hi, W1lo, br1, bz1, bh1, Wx, nullptr, H);

    gru_layer<<<NWG, 1024, 96768, stream>>>(U1hi, U1lo, Wx, hidden + (size_t)B * H,
                                            h1PK, rh1PK,
                                            out + (size_t)T * B * V + (size_t)B * H, cnt1);

    // ---- logits = h1 @ Wout^T + bout (packed-split A) ----
    gemm_logits<<<dim3((V + 127) / 128, T * B / 128), 256, 0, stream>>>(
        h1PK, Wouthi, Woutlo, bout, out, V, H);
}